// Round 11
// baseline (6343.173 us; speedup 1.0000x reference)
//
#include <hip/hip_runtime.h>
#include <hip/hip_bf16.h>
#include <math.h>

// B=512, T=16, DIN=7, D=512, L=2, H=8, HD=64, FF=2048
// Persistent kernel: 32 groups x 16 batch rows, 8 blocks/group (column
// slices). All 16 timesteps x 2 layers in ONE launch; 8-block group
// barriers instead of kernel launches. Cross-XCD correctness: all
// cross-block data + barrier flags via system-scope (LLC) atomics.
// ROUND 11 FIX: rounds 1-4 raced because swz_k zeroed only bar[0..255]
// (256-thread block, "if (tid < 512)") -- groups 16-31 spun on STALE
// counters and fell through every barrier. Zeroing now covers all 512.

typedef __attribute__((__ext_vector_type__(8))) short short8;
typedef __attribute__((__ext_vector_type__(4))) float floatx4;

__device__ inline short8 as_short8(uint4 v){ union U{uint4 u; short8 s;} x; x.u=v; return x.s; }

__device__ inline ushort f2bf(float f){
    __hip_bfloat16 h = __float2bfloat16(f);
    ushort u; __builtin_memcpy(&u, &h, 2); return u;
}

// ---- system-scope (LLC-coherent) access helpers ------------------------
__device__ inline uint32_t sld32(const void* p){
    return __hip_atomic_load((const uint32_t*)p, __ATOMIC_RELAXED, __HIP_MEMORY_SCOPE_SYSTEM);
}
__device__ inline void sst32(void* p, uint32_t v){
    __hip_atomic_store((uint32_t*)p, v, __ATOMIC_RELAXED, __HIP_MEMORY_SCOPE_SYSTEM);
}
__device__ inline unsigned long long sld64(const void* p){
    return __hip_atomic_load((const unsigned long long*)p, __ATOMIC_RELAXED, __HIP_MEMORY_SCOPE_SYSTEM);
}
__device__ inline void sst64(void* p, unsigned long long v){
    __hip_atomic_store((unsigned long long*)p, v, __ATOMIC_RELAXED, __HIP_MEMORY_SCOPE_SYSTEM);
}
__device__ inline float u2f(uint32_t u){ float f; __builtin_memcpy(&f, &u, 4); return f; }
__device__ inline uint32_t f2u(float f){ uint32_t u; __builtin_memcpy(&u, &f, 4); return u; }

// ---- workspace byte offsets --------------------------------------------
#define WS_H      12582912   // float[512*512]      residual (block-private)
#define WS_TMP    13631488   // float[512*512]      pre-LN rows (cross-block)
#define WS_ST1    14680064   // float[512*8*2]      LN1 partial stats
#define WS_ST2    14712832   // float[512*8*2]      LN2 partial stats
#define WS_YPART  14745600   // float[512*8*3]      head partials
#define WS_BAR    14794752   // uint[512]           group barrier counters
#define WS_HBF    14796800   // bf16[512*512]       LN2(l=0) output, bf16
#define WS_ATTN   15321088   // bf16[512*512]       attention output
#define WS_FFBF   15845376   // bf16[512*2048]      relu(ff1) output
#define WS_KC     17942528   // bf16[2*512*8*16*64] K cache (block-private)
#define WS_VC     34719744   // bf16[2*512*8*16*64] V cache (block-private)

// ---------------------------------------------------------------------------
// Weight swizzle: fp32 W[K][N] -> bf16 16B groups of 8 k-consecutive values.
// Group linear index = (kb*4 + q)*N + n, holding W[kb*32+q*8 .. +7][n].
// blockIdx.z = matrix id: (mi = z>>1) 0:qkv 1:out 2:ff1 3:ff2, l = z&1.
// Zeroes ALL 512 group-barrier counters with SYSTEM-scope stores.
// ---------------------------------------------------------------------------
__global__ __launch_bounds__(256)
void swz_k(const float* __restrict__ qkv_w, const float* __restrict__ out_w,
           const float* __restrict__ ff1_w, const float* __restrict__ ff2_w,
           ushort* __restrict__ wsw)
{
    if (blockIdx.x == 0 && blockIdx.y == 0 && blockIdx.z == 0){
        unsigned* bar = (unsigned*)((char*)wsw + WS_BAR);
        for (int i = threadIdx.x; i < 512; i += 256)   // FIX: cover all 512
            sst32(&bar[i], 0u);
    }
    int id = blockIdx.z; int l = id & 1; int mi = id >> 1;
    int K, N; const float* src; size_t doff;
    if (mi == 0)      { K = 512;  N = 1536; src = qkv_w + (size_t)l*786432;  doff = (size_t)l*786432; }
    else if (mi == 1) { K = 512;  N = 512;  src = out_w + (size_t)l*262144;  doff = 1572864 + (size_t)l*262144; }
    else if (mi == 2) { K = 512;  N = 2048; src = ff1_w + (size_t)l*1048576; doff = 2097152 + (size_t)l*1048576; }
    else              { K = 2048; N = 512;  src = ff2_w + (size_t)l*1048576; doff = 4194304 + (size_t)l*1048576; }
    int n0 = blockIdx.x * 64, k0 = blockIdx.y * 32;
    if (n0 >= N || k0 >= K) return;
    __shared__ float tt[32][64];
    int tid = threadIdx.x;
    int c = tid & 63, r = tid >> 6;
    #pragma unroll
    for (int i = 0; i < 8; ++i)
        tt[r + i*4][c] = src[(size_t)(k0 + r + i*4)*N + n0 + c];
    __syncthreads();
    int q = tid >> 6, n = tid & 63;
    union { ushort s[8]; uint4 v; } pk;
    #pragma unroll
    for (int i = 0; i < 8; ++i) pk.s[i] = f2bf(tt[q*8 + i][n]);
    ((uint4*)(wsw + doff))[(size_t)((k0 >> 5)*4 + q)*N + n0 + n] = pk.v;
}

// ---------------------------------------------------------------------------
// The persistent kernel. grid = 256 blocks x 256 threads.
// group g = blockIdx & 31 (16 rows: b0 = g*16); member j = blockIdx >> 5.
// Members of group g are bid = g + 32*j, all congruent mod 8 -> same XCD
// under round-robin (perf only; correctness via system-scope atomics).
// A-tiles (16 rows x K) live in LDS with XOR swizzle: slot(c,m) = c*16 + (m^(c&15)).
// ---------------------------------------------------------------------------
#define ALDS(c, m) aLds[(((c) << 4)) + (((m) ^ ((c) & 15)))]

__global__ __launch_bounds__(256, 1)
void mega_k(const float* __restrict__ x, const float* __restrict__ ip_w,
            const float* __restrict__ ip_b, const float* __restrict__ qkv_b,
            const float* __restrict__ out_b, const float* __restrict__ ln1_s,
            const float* __restrict__ ln1_b, const float* __restrict__ ff_b1,
            const float* __restrict__ ff_b2, const float* __restrict__ ln2_s,
            const float* __restrict__ ln2_b, const float* __restrict__ hw,
            const float* __restrict__ hb, float* __restrict__ out,
            char* __restrict__ ws)
{
    const ushort* wsw = (const ushort*)ws;
    float* h     = (float*)(ws + WS_H);
    float* tmp   = (float*)(ws + WS_TMP);
    float* st1   = (float*)(ws + WS_ST1);
    float* st2   = (float*)(ws + WS_ST2);
    float* ypart = (float*)(ws + WS_YPART);
    unsigned* bar = (unsigned*)(ws + WS_BAR);
    __hip_bfloat16* hbf    = (__hip_bfloat16*)(ws + WS_HBF);
    __hip_bfloat16* attnbf = (__hip_bfloat16*)(ws + WS_ATTN);
    __hip_bfloat16* ffbf   = (__hip_bfloat16*)(ws + WS_FFBF);
    __hip_bfloat16* kc0    = (__hip_bfloat16*)(ws + WS_KC);
    __hip_bfloat16* vc0    = (__hip_bfloat16*)(ws + WS_VC);

    const int g  = blockIdx.x & 31;   // group (16 batch rows)
    const int j  = blockIdx.x >> 5;   // column-slice member 0..7
    const int b0 = g * 16;
    const int tid  = threadIdx.x;
    const int lane = tid & 63, w = tid >> 6;
    const int qd = lane >> 4, ln = lane & 15;
    unsigned* cnt = bar + g*16;
    unsigned epoch = 0;

    __shared__ uint4 aLds[256*16];          // 64 KiB (K<=2048 A-tile)
    __shared__ float qLds[16][68];          // q rows for attention (+pad)
    __shared__ float yLds[16][3];
    __shared__ float meanLds[16], rstdLds[16];
    __shared__ float redS[4][4][4], redQ[4][4][4];

    auto gbar = [&]() {
        __syncthreads();                    // all waves' stores drained (vmcnt0)
        epoch += 8;
        if (tid == 0){
            __threadfence_system();
            __hip_atomic_fetch_add(cnt, 1u, __ATOMIC_SEQ_CST, __HIP_MEMORY_SCOPE_SYSTEM);
            while (__hip_atomic_load(cnt, __ATOMIC_ACQUIRE, __HIP_MEMORY_SCOPE_SYSTEM) < epoch)
                __builtin_amdgcn_s_sleep(8);
            __threadfence_system();
        }
        __syncthreads();
    };

    for (int t = 0; t < 16; ++t){
        for (int l = 0; l < 2; ++l){
            __hip_bfloat16* kc = kc0 + (size_t)l*4194304;
            __hip_bfloat16* vc = vc0 + (size_t)l*4194304;

            // ============ P1: build A (layer input) + QKV + attention =====
            if (l == 1){
                const unsigned long long* src = (const unsigned long long*)hbf;
                #pragma unroll
                for (int i = 0; i < 4; ++i){
                    int e = tid + i*256; int m = e >> 6, cg = e & 63;
                    size_t gi = ((size_t)(b0+m)*64 + cg)*2;
                    union { unsigned long long q[2]; uint4 v; } u;
                    u.q[0] = sld64(src + gi); u.q[1] = sld64(src + gi + 1);
                    ALDS(cg, m) = u.v;
                }
            } else {
                if (t > 0){
                    if (tid < 48){
                        int r = tid / 3, c = tid - r*3;
                        float yv = hb[c];
                        #pragma unroll
                        for (int jj = 0; jj < 8; ++jj)
                            yv += u2f(sld32(&ypart[((size_t)(b0+r)*8 + jj)*3 + c]));
                        yLds[r][c] = yv;
                        if (j == 0)
                            out[((size_t)(b0+r)*16 + (t-1))*3 + c] = yv;
                    }
                    __syncthreads();
                }
                // embed: h = x@ip_w + ip_b + pe[t] (cols 4..6 = y feedback for t>0)
                #pragma unroll
                for (int i = 0; i < 4; ++i){
                    int e = tid + i*256; int m = e >> 6, cg = e & 63;
                    int b = b0 + m;
                    const float* xr = x + ((size_t)b*16 + t)*7;
                    float f4, f5, f6;
                    if (t == 0){ f4 = xr[4]; f5 = xr[5]; f6 = xr[6]; }
                    else { f4 = yLds[m][0]; f5 = yLds[m][1]; f6 = yLds[m][2]; }
                    float x0 = xr[0], x1 = xr[1], x2 = xr[2], x3 = xr[3];
                    float hv[8];
                    union { ushort s[8]; uint4 v; } pk;
                    #pragma unroll
                    for (int k = 0; k < 8; ++k){
                        int d = cg*8 + k;
                        int e2 = d & ~1;
                        float div = expf(-(float)e2 * (9.210340371976184f / 512.0f));
                        float arg = (float)t * div;
                        float pe = (d & 1) ? cosf(arg) : sinf(arg);
                        float acc = ip_b[d] + pe
                            + x0*ip_w[0*512+d] + x1*ip_w[1*512+d]
                            + x2*ip_w[2*512+d] + x3*ip_w[3*512+d]
                            + f4*ip_w[4*512+d] + f5*ip_w[5*512+d] + f6*ip_w[6*512+d];
                        hv[k] = acc;
                        pk.s[k] = f2bf(acc);
                    }
                    ALDS(cg, m) = pk.v;
                    if ((cg >> 3) == j){          // this block's column slice
                        float4* hp = (float4*)(h + (size_t)(b0+m)*512 + cg*8);
                        hp[0] = make_float4(hv[0],hv[1],hv[2],hv[3]);
                        hp[1] = make_float4(hv[4],hv[5],hv[6],hv[7]);
                    }
                }
            }
            __syncthreads();

            { // QKV gemm: this block: q/k/v 64-col chunks of head j
                const uint4* Bg = (const uint4*)(wsw + (size_t)l*786432);
                floatx4 acc[3] = {};
                int c64 = w*16;
                for (int kb = 0; kb < 16; ++kb){
                    short8 af = as_short8(ALDS(kb*4 + qd, ln));
                    #pragma unroll
                    for (int s = 0; s < 3; ++s){
                        int n = s*512 + j*64 + c64 + ln;
                        short8 bf = as_short8(Bg[(size_t)(kb*4 + qd)*1536 + n]);
                        acc[s] = __builtin_amdgcn_mfma_f32_16x16x32_bf16(af, bf, acc[s], 0, 0, 0);
                    }
                }
                #pragma unroll
                for (int s = 0; s < 3; ++s){
                    #pragma unroll
                    for (int r = 0; r < 4; ++r){
                        int row = qd*4 + r;
                        int cc = c64 + ln;              // 0..63 within head j
                        int n = s*512 + j*64 + cc;
                        float v = acc[s][r] + qkv_b[l*1536 + n];
                        int b = b0 + row;
                        if (s == 0) qLds[row][cc] = v;
                        else if (s == 1) kc[(((size_t)b*8 + j)*16 + t)*64 + cc] = __float2bfloat16(v);
                        else             vc[(((size_t)b*8 + j)*16 + t)*64 + cc] = __float2bfloat16(v);
                    }
                }
            }
            __syncthreads();

            { // attention head j, rows of this group (wave w: rows w*4..w*4+3)
                #pragma unroll
                for (int i = 0; i < 4; ++i){
                    int m = w*4 + i;
                    int b = b0 + m;
                    float q = qLds[m][lane];
                    const __hip_bfloat16* kp = kc + ((size_t)b*8 + j)*1024;
                    const __hip_bfloat16* vp = vc + ((size_t)b*8 + j)*1024;
                    float mr = -1e30f, s = 0.0f, o = 0.0f;
                    for (int jj = 0; jj <= t; ++jj){
                        float p = q * __bfloat162float(kp[jj*64 + lane]);
                        #pragma unroll
                        for (int off = 32; off; off >>= 1) p += __shfl_xor(p, off);
                        p *= 0.125f;
                        float nm = fmaxf(mr, p);
                        float sc = __expf(mr - nm);
                        float e  = __expf(p - nm);
                        s = s*sc + e;
                        o = o*sc + e*__bfloat162float(vp[jj*64 + lane]);
                        mr = nm;
                    }
                    float ov = o / s;
                    float ovp = __shfl_xor(ov, 1);     // partner lane's value
                    if (!(lane & 1)){
                        uint32_t pk2 = (uint32_t)f2bf(ov) | ((uint32_t)f2bf(ovp) << 16);
                        sst32((uint32_t*)attnbf + (((size_t)b*512 + j*64 + lane) >> 1), pk2);
                    }
                }
            }
            gbar();

            // ============ P2: out-proj (+bias+resid) -> tmp + LN1 partials =
            {
                const unsigned long long* src = (const unsigned long long*)attnbf;
                #pragma unroll
                for (int i = 0; i < 4; ++i){
                    int e = tid + i*256; int m = e >> 6, cg = e & 63;
                    size_t gi = ((size_t)(b0+m)*64 + cg)*2;
                    union { unsigned long long q[2]; uint4 v; } u;
                    u.q[0] = sld64(src + gi); u.q[1] = sld64(src + gi + 1);
                    ALDS(cg, m) = u.v;
                }
                __syncthreads();
                const uint4* Bg = (const uint4*)(wsw + 1572864 + (size_t)l*262144);
                floatx4 acc = {};
                int nb = j*64 + w*16;
                for (int kb = 0; kb < 16; ++kb){
                    short8 af = as_short8(ALDS(kb*4 + qd, ln));
                    short8 bf = as_short8(Bg[(size_t)(kb*4 + qd)*512 + nb + ln]);
                    acc = __builtin_amdgcn_mfma_f32_16x16x32_bf16(af, bf, acc, 0, 0, 0);
                }
                int n = nb + ln;
                float psum[4], psq[4];
                #pragma unroll
                for (int r = 0; r < 4; ++r){
                    int row = qd*4 + r, b = b0 + row;
                    float v = acc[r] + out_b[l*512 + n] + h[(size_t)b*512 + n];
                    sst32(&tmp[(size_t)b*512 + n], f2u(v));
                    psum[r] = v; psq[r] = v*v;
                }
                #pragma unroll
                for (int off = 1; off < 16; off <<= 1){
                    #pragma unroll
                    for (int r = 0; r < 4; ++r){
                        psum[r] += __shfl_xor(psum[r], off);
                        psq[r]  += __shfl_xor(psq[r],  off);
                    }
                }
                if (ln == 0){
                    #pragma unroll
                    for (int r = 0; r < 4; ++r){ redS[w][qd][r] = psum[r]; redQ[w][qd][r] = psq[r]; }
                }
                __syncthreads();
                if (tid < 16){
                    int q2 = tid >> 2, r2 = tid & 3;
                    float sm = redS[0][q2][r2]+redS[1][q2][r2]+redS[2][q2][r2]+redS[3][q2][r2];
                    float sq = redQ[0][q2][r2]+redQ[1][q2][r2]+redQ[2][q2][r2]+redQ[3][q2][r2];
                    union { float f[2]; unsigned long long q; } u;
                    u.f[0] = sm; u.f[1] = sq;
                    sst64(&st1[((size_t)(b0+tid)*8 + j)*2], u.q);
                }
            }
            gbar();

            // ============ P3: LN1 finalize + FF1 (relu) -> ffbf ============
            {
                if (tid < 16){
                    float sm = 0.f, sq = 0.f;
                    #pragma unroll
                    for (int jj = 0; jj < 8; ++jj){
                        union { unsigned long long q; float f[2]; } u;
                        u.q = sld64(&st1[((size_t)(b0+tid)*8 + jj)*2]);
                        sm += u.f[0]; sq += u.f[1];
                    }
                    float mean = sm * (1.0f/512.0f);
                    float var  = sq * (1.0f/512.0f) - mean*mean;
                    meanLds[tid] = mean;
                    rstdLds[tid] = rsqrtf(var + 1e-5f);
                }
                __syncthreads();
                #pragma unroll
                for (int i = 0; i < 4; ++i){
                    int e = tid + i*256; int m = e >> 6, cg = e & 63;
                    int b = b0 + m;
                    float mean = meanLds[m], rs = rstdLds[m];
                    const float* tp = tmp + (size_t)b*512 + cg*8;
                    union { unsigned long long q[4]; float f[8]; } uu;
                    uu.q[0] = sld64(tp);     uu.q[1] = sld64(tp + 2);
                    uu.q[2] = sld64(tp + 4); uu.q[3] = sld64(tp + 6);
                    float hn[8];
                    union { ushort s[8]; uint4 v; } pk;
                    #pragma unroll
                    for (int k = 0; k < 8; ++k){
                        int d = cg*8 + k;
                        float nv = (uu.f[k] - mean)*rs*ln1_s[l*512 + d] + ln1_b[l*512 + d];
                        hn[k] = nv;
                        pk.s[k] = f2bf(nv);
                    }
                    ALDS(cg, m) = pk.v;
                    if ((cg >> 3) == j){     // materialize LN1-out (FF2 residual)
                        float4* hp = (float4*)(h + (size_t)b*512 + cg*8);
                        hp[0] = make_float4(hn[0],hn[1],hn[2],hn[3]);
                        hp[1] = make_float4(hn[4],hn[5],hn[6],hn[7]);
                    }
                }
                __syncthreads();
                const uint4* Bg = (const uint4*)(wsw + 2097152 + (size_t)l*1048576);
                floatx4 acc[4] = {};
                int nb = j*256 + w*64;
                for (int kb = 0; kb < 16; ++kb){
                    short8 af = as_short8(ALDS(kb*4 + qd, ln));
                    #pragma unroll
                    for (int c = 0; c < 4; ++c){
                        short8 bf = as_short8(Bg[(size_t)(kb*4 + qd)*2048 + nb + c*16 + ln]);
                        acc[c] = __builtin_amdgcn_mfma_f32_16x16x32_bf16(af, bf, acc[c], 0, 0, 0);
                    }
                }
                #pragma unroll
                for (int c = 0; c < 4; ++c){
                    #pragma unroll
                    for (int r = 0; r < 4; ++r){
                        int row = qd*4 + r, b = b0 + row;
                        int n = nb + c*16 + ln;
                        float v  = acc[c][r] + ff_b1[l*2048 + n];
                        float vr = fmaxf(v, 0.0f);
                        float vp = __shfl_xor(vr, 1);
                        if (!(ln & 1)){
                            uint32_t pk2 = (uint32_t)f2bf(vr) | ((uint32_t)f2bf(vp) << 16);
                            sst32((uint32_t*)ffbf + (((size_t)b*2048 + n) >> 1), pk2);
                        }
                    }
                }
            }
            gbar();

            // ============ P4: FF2 (+bias+resid) -> tmp + LN2 partials ======
            {
                const unsigned long long* src = (const unsigned long long*)ffbf;
                #pragma unroll
                for (int i = 0; i < 16; ++i){
                    int e = tid + i*256; int m = e >> 8, cg = e & 255;
                    size_t gi = ((size_t)(b0+m)*256 + cg)*2;
                    union { unsigned long long q[2]; uint4 v; } u;
                    u.q[0] = sld64(src + gi); u.q[1] = sld64(src + gi + 1);
                    ALDS(cg, m) = u.v;
                }
                __syncthreads();
                const uint4* Bg = (const uint4*)(wsw + 4194304 + (size_t)l*1048576);
                floatx4 acc = {};
                int nb = j*64 + w*16;
                for (int kb = 0; kb < 64; ++kb){
                    short8 af = as_short8(ALDS(kb*4 + qd, ln));
                    short8 bf = as_short8(Bg[(size_t)(kb*4 + qd)*512 + nb + ln]);
                    acc = __builtin_amdgcn_mfma_f32_16x16x32_bf16(af, bf, acc, 0, 0, 0);
                }
                int n = nb + ln;
                float psum[4], psq[4];
                #pragma unroll
                for (int r = 0; r < 4; ++r){
                    int row = qd*4 + r, b = b0 + row;
                    float v = acc[r] + ff_b2[l*512 + n] + h[(size_t)b*512 + n];
                    sst32(&tmp[(size_t)b*512 + n], f2u(v));
                    psum[r] = v; psq[r] = v*v;
                }
                #pragma unroll
                for (int off = 1; off < 16; off <<= 1){
                    #pragma unroll
                    for (int r = 0; r < 4; ++r){
                        psum[r] += __shfl_xor(psum[r], off);
                        psq[r]  += __shfl_xor(psq[r],  off);
                    }
                }
                if (ln == 0){
                    #pragma unroll
                    for (int r = 0; r < 4; ++r){ redS[w][qd][r] = psum[r]; redQ[w][qd][r] = psq[r]; }
                }
                __syncthreads();
                if (tid < 16){
                    int q2 = tid >> 2, r2 = tid & 3;
                    float sm = redS[0][q2][r2]+redS[1][q2][r2]+redS[2][q2][r2]+redS[3][q2][r2];
                    float sq = redQ[0][q2][r2]+redQ[1][q2][r2]+redQ[2][q2][r2]+redQ[3][q2][r2];
                    union { float f[2]; unsigned long long q; } u;
                    u.f[0] = sm; u.f[1] = sq;
                    sst64(&st2[((size_t)(b0+tid)*8 + j)*2], u.q);
                }
            }
            gbar();

            // ============ P5: LN2 -> (h,hbf) for l=0 | head partials l=1 ===
            {
                if (tid < 16){
                    float sm = 0.f, sq = 0.f;
                    #pragma unroll
                    for (int jj = 0; jj < 8; ++jj){
                        union { unsigned long long q; float f[2]; } u;
                        u.q = sld64(&st2[((size_t)(b0+tid)*8 + jj)*2]);
                        sm += u.f[0]; sq += u.f[1];
                    }
                    float mean = sm * (1.0f/512.0f);
                    float var  = sq * (1.0f/512.0f) - mean*mean;
                    meanLds[tid] = mean;
                    rstdLds[tid] = rsqrtf(var + 1e-5f);
                }
                __syncthreads();
                int r = tid >> 4, q16 = tid & 15;
                int b = b0 + r;
                int d0 = j*64 + q16*4;
                const float* tp = tmp + (size_t)b*512 + d0;
                union { unsigned long long q[2]; float f[4]; } uu;
                uu.q[0] = sld64(tp); uu.q[1] = sld64(tp + 2);
                float mean = meanLds[r], rs = rstdLds[r];
                float hn0 = (uu.f[0] - mean)*rs*ln2_s[l*512 + d0+0] + ln2_b[l*512 + d0+0];
                float hn1 = (uu.f[1] - mean)*rs*ln2_s[l*512 + d0+1] + ln2_b[l*512 + d0+1];
                float hn2 = (uu.f[2] - mean)*rs*ln2_s[l*512 + d0+2] + ln2_b[l*512 + d0+2];
                float hn3 = (uu.f[3] - mean)*rs*ln2_s[l*512 + d0+3] + ln2_b[l*512 + d0+3];
                if (l == 0){
                    *(float4*)(h + (size_t)b*512 + d0) = make_float4(hn0,hn1,hn2,hn3);
                    union { ushort s[4]; unsigned long long q; } pk;
                    pk.s[0]=f2bf(hn0); pk.s[1]=f2bf(hn1); pk.s[2]=f2bf(hn2); pk.s[3]=f2bf(hn3);
                    sst64((ushort*)hbf + (size_t)b*512 + d0, pk.q);
                } else {
                    float s0 = hn0*hw[(d0+0)*3+0] + hn1*hw[(d0+1)*3+0] + hn2*hw[(d0+2)*3+0] + hn3*hw[(d0+3)*3+0];
                    float s1 = hn0*hw[(d0+0)*3+1] + hn1*hw[(d0+1)*3+1] + hn2*hw[(d0+2)*3+1] + hn3*hw[(d0+3)*3+1];
                    float s2 = hn0*hw[(d0+0)*3+2] + hn1*hw[(d0+1)*3+2] + hn2*hw[(d0+2)*3+2] + hn3*hw[(d0+3)*3+2];
                    #pragma unroll
                    for (int off = 1; off < 16; off <<= 1){
                        s0 += __shfl_xor(s0, off);
                        s1 += __shfl_xor(s1, off);
                        s2 += __shfl_xor(s2, off);
                    }
                    if (q16 == 0){
                        float* yp = ypart + ((size_t)b*8 + j)*3;
                        sst32(yp + 0, f2u(s0));
                        sst32(yp + 1, f2u(s1));
                        sst32(yp + 2, f2u(s2));
                    }
                }
            }
            gbar();
        } // l
    } // t

    // final head output for t=15 (ypart released by the last gbar)
    if (j == 0 && tid < 48){
        int r = tid / 3, c = tid - r*3;
        float yv = hb[c];
        #pragma unroll
        for (int jj = 0; jj < 8; ++jj)
            yv += u2f(sld32(&ypart[((size_t)(b0+r)*8 + jj)*3 + c]));
        out[((size_t)(b0+r)*16 + 15)*3 + c] = yv;
    }
}

// ---------------------------------------------------------------------------
extern "C" void kernel_launch(void* const* d_in, const int* in_sizes, int n_in,
                              void* d_out, int out_size, void* d_ws, size_t ws_size,
                              hipStream_t stream)
{
    const float* x     = (const float*)d_in[0];
    const float* ip_w  = (const float*)d_in[1];
    const float* ip_b  = (const float*)d_in[2];
    const float* qkv_w = (const float*)d_in[3];
    const float* qkv_b = (const float*)d_in[4];
    const float* out_w = (const float*)d_in[5];
    const float* out_b = (const float*)d_in[6];
    const float* ln1_s = (const float*)d_in[7];
    const float* ln1_b = (const float*)d_in[8];
    const float* ff_w1 = (const float*)d_in[9];
    const float* ff_b1 = (const float*)d_in[10];
    const float* ff_w2 = (const float*)d_in[11];
    const float* ff_b2 = (const float*)d_in[12];
    const float* ln2_s = (const float*)d_in[13];
    const float* ln2_b = (const float*)d_in[14];
    const float* hw    = (const float*)d_in[15];
    const float* hb    = (const float*)d_in[16];
    float* outp = (float*)d_out;
    char* wsc   = (char*)d_ws;

    swz_k<<<dim3(32, 64, 8), 256, 0, stream>>>(qkv_w, out_w, ff_w1, ff_w2, (ushort*)d_ws);

    // Plain launch (NO cooperative launch: not graph-capturable). 256 blocks
    // with ~70KB LDS each are all-resident on 256 CUs -> no barrier deadlock.
    mega_k<<<dim3(256), dim3(256), 0, stream>>>(
        x, ip_w, ip_b, qkv_b, out_b, ln1_s, ln1_b,
        ff_b1, ff_b2, ln2_s, ln2_b, hw, hb, outp, wsc);
}

// Round 12
// 3532.121 us; speedup vs baseline: 1.7959x; 1.7959x over previous
//
#include <hip/hip_runtime.h>
#include <hip/hip_bf16.h>
#include <math.h>

// B=512, T=16, DIN=7, D=512, L=2, H=8, HD=64, FF=2048
// Persistent kernel: 32 groups x 16 batch rows, 8 blocks/group (column
// slices). All 16 timesteps x 2 layers in ONE launch; 8-block group
// barriers instead of kernel launches. Cross-XCD correctness: all
// cross-block data + barrier flags via system-scope (LLC) atomics.
// Round 12: gbar drops BOTH __threadfence_system() calls and relaxes the
// flag atomics. They are redundant: all cross-block data uses sc-bypass
// system-scope ops served at the LLC, and __syncthreads' vmcnt(0) drain
// is the release; bypass loads after the barrier are the acquire. The
// fences lowered to cache-wide wbl2/inv (256 blocks x 160 barriers) and
// also evicted the L2-resident weights every phase.

typedef __attribute__((__ext_vector_type__(8))) short short8;
typedef __attribute__((__ext_vector_type__(4))) float floatx4;

__device__ inline short8 as_short8(uint4 v){ union U{uint4 u; short8 s;} x; x.u=v; return x.s; }

__device__ inline ushort f2bf(float f){
    __hip_bfloat16 h = __float2bfloat16(f);
    ushort u; __builtin_memcpy(&u, &h, 2); return u;
}

// ---- system-scope (LLC-coherent) access helpers ------------------------
__device__ inline uint32_t sld32(const void* p){
    return __hip_atomic_load((const uint32_t*)p, __ATOMIC_RELAXED, __HIP_MEMORY_SCOPE_SYSTEM);
}
__device__ inline void sst32(void* p, uint32_t v){
    __hip_atomic_store((uint32_t*)p, v, __ATOMIC_RELAXED, __HIP_MEMORY_SCOPE_SYSTEM);
}
__device__ inline unsigned long long sld64(const void* p){
    return __hip_atomic_load((const unsigned long long*)p, __ATOMIC_RELAXED, __HIP_MEMORY_SCOPE_SYSTEM);
}
__device__ inline void sst64(void* p, unsigned long long v){
    __hip_atomic_store((unsigned long long*)p, v, __ATOMIC_RELAXED, __HIP_MEMORY_SCOPE_SYSTEM);
}
__device__ inline float u2f(uint32_t u){ float f; __builtin_memcpy(&f, &u, 4); return f; }
__device__ inline uint32_t f2u(float f){ uint32_t u; __builtin_memcpy(&u, &f, 4); return u; }

// ---- workspace byte offsets --------------------------------------------
#define WS_H      12582912   // float[512*512]      residual (block-private)
#define WS_TMP    13631488   // float[512*512]      pre-LN rows (cross-block)
#define WS_ST1    14680064   // float[512*8*2]      LN1 partial stats
#define WS_ST2    14712832   // float[512*8*2]      LN2 partial stats
#define WS_YPART  14745600   // float[512*8*3]      head partials
#define WS_BAR    14794752   // uint[512]           group barrier counters
#define WS_HBF    14796800   // bf16[512*512]       LN2(l=0) output, bf16
#define WS_ATTN   15321088   // bf16[512*512]       attention output
#define WS_FFBF   15845376   // bf16[512*2048]      relu(ff1) output
#define WS_KC     17942528   // bf16[2*512*8*16*64] K cache (block-private)
#define WS_VC     34719744   // bf16[2*512*8*16*64] V cache (block-private)

// ---------------------------------------------------------------------------
// Weight swizzle: fp32 W[K][N] -> bf16 16B groups of 8 k-consecutive values.
// Group linear index = (kb*4 + q)*N + n, holding W[kb*32+q*8 .. +7][n].
// blockIdx.z = matrix id: (mi = z>>1) 0:qkv 1:out 2:ff1 3:ff2, l = z&1.
// Zeroes ALL 512 group-barrier counters with SYSTEM-scope stores.
// ---------------------------------------------------------------------------
__global__ __launch_bounds__(256)
void swz_k(const float* __restrict__ qkv_w, const float* __restrict__ out_w,
           const float* __restrict__ ff1_w, const float* __restrict__ ff2_w,
           ushort* __restrict__ wsw)
{
    if (blockIdx.x == 0 && blockIdx.y == 0 && blockIdx.z == 0){
        unsigned* bar = (unsigned*)((char*)wsw + WS_BAR);
        for (int i = threadIdx.x; i < 512; i += 256)   // cover all 512
            sst32(&bar[i], 0u);
    }
    int id = blockIdx.z; int l = id & 1; int mi = id >> 1;
    int K, N; const float* src; size_t doff;
    if (mi == 0)      { K = 512;  N = 1536; src = qkv_w + (size_t)l*786432;  doff = (size_t)l*786432; }
    else if (mi == 1) { K = 512;  N = 512;  src = out_w + (size_t)l*262144;  doff = 1572864 + (size_t)l*262144; }
    else if (mi == 2) { K = 512;  N = 2048; src = ff1_w + (size_t)l*1048576; doff = 2097152 + (size_t)l*1048576; }
    else              { K = 2048; N = 512;  src = ff2_w + (size_t)l*1048576; doff = 4194304 + (size_t)l*1048576; }
    int n0 = blockIdx.x * 64, k0 = blockIdx.y * 32;
    if (n0 >= N || k0 >= K) return;
    __shared__ float tt[32][64];
    int tid = threadIdx.x;
    int c = tid & 63, r = tid >> 6;
    #pragma unroll
    for (int i = 0; i < 8; ++i)
        tt[r + i*4][c] = src[(size_t)(k0 + r + i*4)*N + n0 + c];
    __syncthreads();
    int q = tid >> 6, n = tid & 63;
    union { ushort s[8]; uint4 v; } pk;
    #pragma unroll
    for (int i = 0; i < 8; ++i) pk.s[i] = f2bf(tt[q*8 + i][n]);
    ((uint4*)(wsw + doff))[(size_t)((k0 >> 5)*4 + q)*N + n0 + n] = pk.v;
}

// ---------------------------------------------------------------------------
// The persistent kernel. grid = 256 blocks x 256 threads.
// group g = blockIdx & 31 (16 rows: b0 = g*16); member j = blockIdx >> 5.
// Members of group g are bid = g + 32*j, all congruent mod 8 -> same XCD
// under round-robin (perf only; correctness via system-scope atomics).
// A-tiles (16 rows x K) live in LDS with XOR swizzle: slot(c,m) = c*16 + (m^(c&15)).
// ---------------------------------------------------------------------------
#define ALDS(c, m) aLds[(((c) << 4)) + (((m) ^ ((c) & 15)))]

__global__ __launch_bounds__(256, 1)
void mega_k(const float* __restrict__ x, const float* __restrict__ ip_w,
            const float* __restrict__ ip_b, const float* __restrict__ qkv_b,
            const float* __restrict__ out_b, const float* __restrict__ ln1_s,
            const float* __restrict__ ln1_b, const float* __restrict__ ff_b1,
            const float* __restrict__ ff_b2, const float* __restrict__ ln2_s,
            const float* __restrict__ ln2_b, const float* __restrict__ hw,
            const float* __restrict__ hb, float* __restrict__ out,
            char* __restrict__ ws)
{
    const ushort* wsw = (const ushort*)ws;
    float* h     = (float*)(ws + WS_H);
    float* tmp   = (float*)(ws + WS_TMP);
    float* st1   = (float*)(ws + WS_ST1);
    float* st2   = (float*)(ws + WS_ST2);
    float* ypart = (float*)(ws + WS_YPART);
    unsigned* bar = (unsigned*)(ws + WS_BAR);
    __hip_bfloat16* hbf    = (__hip_bfloat16*)(ws + WS_HBF);
    __hip_bfloat16* attnbf = (__hip_bfloat16*)(ws + WS_ATTN);
    __hip_bfloat16* ffbf   = (__hip_bfloat16*)(ws + WS_FFBF);
    __hip_bfloat16* kc0    = (__hip_bfloat16*)(ws + WS_KC);
    __hip_bfloat16* vc0    = (__hip_bfloat16*)(ws + WS_VC);

    const int g  = blockIdx.x & 31;   // group (16 batch rows)
    const int j  = blockIdx.x >> 5;   // column-slice member 0..7
    const int b0 = g * 16;
    const int tid  = threadIdx.x;
    const int lane = tid & 63, w = tid >> 6;
    const int qd = lane >> 4, ln = lane & 15;
    unsigned* cnt = bar + g*16;
    unsigned epoch = 0;

    __shared__ uint4 aLds[256*16];          // 64 KiB (K<=2048 A-tile)
    __shared__ float qLds[16][68];          // q rows for attention (+pad)
    __shared__ float yLds[16][3];
    __shared__ float meanLds[16], rstdLds[16];
    __shared__ float redS[4][4][4], redQ[4][4][4];

    auto gbar = [&]() {
        __syncthreads();      // each wave: s_waitcnt vmcnt(0) -> bypass-stores at LLC
        epoch += 8;
        if (tid == 0){
            __hip_atomic_fetch_add(cnt, 1u, __ATOMIC_RELAXED, __HIP_MEMORY_SCOPE_SYSTEM);
            while (__hip_atomic_load(cnt, __ATOMIC_RELAXED, __HIP_MEMORY_SCOPE_SYSTEM) < epoch)
                __builtin_amdgcn_s_sleep(8);
        }
        __syncthreads();      // post-barrier bypass-loads read fresh LLC data
    };

    for (int t = 0; t < 16; ++t){
        for (int l = 0; l < 2; ++l){
            __hip_bfloat16* kc = kc0 + (size_t)l*4194304;
            __hip_bfloat16* vc = vc0 + (size_t)l*4194304;

            // ============ P1: build A (layer input) + QKV + attention =====
            if (l == 1){
                const unsigned long long* src = (const unsigned long long*)hbf;
                #pragma unroll
                for (int i = 0; i < 4; ++i){
                    int e = tid + i*256; int m = e >> 6, cg = e & 63;
                    size_t gi = ((size_t)(b0+m)*64 + cg)*2;
                    union { unsigned long long q[2]; uint4 v; } u;
                    u.q[0] = sld64(src + gi); u.q[1] = sld64(src + gi + 1);
                    ALDS(cg, m) = u.v;
                }
            } else {
                if (t > 0){
                    if (tid < 48){
                        int r = tid / 3, c = tid - r*3;
                        float yv = hb[c];
                        #pragma unroll
                        for (int jj = 0; jj < 8; ++jj)
                            yv += u2f(sld32(&ypart[((size_t)(b0+r)*8 + jj)*3 + c]));
                        yLds[r][c] = yv;
                        if (j == 0)
                            out[((size_t)(b0+r)*16 + (t-1))*3 + c] = yv;
                    }
                    __syncthreads();
                }
                // embed: h = x@ip_w + ip_b + pe[t] (cols 4..6 = y feedback for t>0)
                #pragma unroll
                for (int i = 0; i < 4; ++i){
                    int e = tid + i*256; int m = e >> 6, cg = e & 63;
                    int b = b0 + m;
                    const float* xr = x + ((size_t)b*16 + t)*7;
                    float f4, f5, f6;
                    if (t == 0){ f4 = xr[4]; f5 = xr[5]; f6 = xr[6]; }
                    else { f4 = yLds[m][0]; f5 = yLds[m][1]; f6 = yLds[m][2]; }
                    float x0 = xr[0], x1 = xr[1], x2 = xr[2], x3 = xr[3];
                    float hv[8];
                    union { ushort s[8]; uint4 v; } pk;
                    #pragma unroll
                    for (int k = 0; k < 8; ++k){
                        int d = cg*8 + k;
                        int e2 = d & ~1;
                        float div = expf(-(float)e2 * (9.210340371976184f / 512.0f));
                        float arg = (float)t * div;
                        float pe = (d & 1) ? cosf(arg) : sinf(arg);
                        float acc = ip_b[d] + pe
                            + x0*ip_w[0*512+d] + x1*ip_w[1*512+d]
                            + x2*ip_w[2*512+d] + x3*ip_w[3*512+d]
                            + f4*ip_w[4*512+d] + f5*ip_w[5*512+d] + f6*ip_w[6*512+d];
                        hv[k] = acc;
                        pk.s[k] = f2bf(acc);
                    }
                    ALDS(cg, m) = pk.v;
                    if ((cg >> 3) == j){          // this block's column slice
                        float4* hp = (float4*)(h + (size_t)(b0+m)*512 + cg*8);
                        hp[0] = make_float4(hv[0],hv[1],hv[2],hv[3]);
                        hp[1] = make_float4(hv[4],hv[5],hv[6],hv[7]);
                    }
                }
            }
            __syncthreads();

            { // QKV gemm: this block: q/k/v 64-col chunks of head j
                const uint4* Bg = (const uint4*)(wsw + (size_t)l*786432);
                floatx4 acc[3] = {};
                int c64 = w*16;
                for (int kb = 0; kb < 16; ++kb){
                    short8 af = as_short8(ALDS(kb*4 + qd, ln));
                    #pragma unroll
                    for (int s = 0; s < 3; ++s){
                        int n = s*512 + j*64 + c64 + ln;
                        short8 bf = as_short8(Bg[(size_t)(kb*4 + qd)*1536 + n]);
                        acc[s] = __builtin_amdgcn_mfma_f32_16x16x32_bf16(af, bf, acc[s], 0, 0, 0);
                    }
                }
                #pragma unroll
                for (int s = 0; s < 3; ++s){
                    #pragma unroll
                    for (int r = 0; r < 4; ++r){
                        int row = qd*4 + r;
                        int cc = c64 + ln;              // 0..63 within head j
                        int n = s*512 + j*64 + cc;
                        float v = acc[s][r] + qkv_b[l*1536 + n];
                        int b = b0 + row;
                        if (s == 0) qLds[row][cc] = v;
                        else if (s == 1) kc[(((size_t)b*8 + j)*16 + t)*64 + cc] = __float2bfloat16(v);
                        else             vc[(((size_t)b*8 + j)*16 + t)*64 + cc] = __float2bfloat16(v);
                    }
                }
            }
            __syncthreads();

            { // attention head j, rows of this group (wave w: rows w*4..w*4+3)
                #pragma unroll
                for (int i = 0; i < 4; ++i){
                    int m = w*4 + i;
                    int b = b0 + m;
                    float q = qLds[m][lane];
                    const __hip_bfloat16* kp = kc + ((size_t)b*8 + j)*1024;
                    const __hip_bfloat16* vp = vc + ((size_t)b*8 + j)*1024;
                    float mr = -1e30f, s = 0.0f, o = 0.0f;
                    for (int jj = 0; jj <= t; ++jj){
                        float p = q * __bfloat162float(kp[jj*64 + lane]);
                        #pragma unroll
                        for (int off = 32; off; off >>= 1) p += __shfl_xor(p, off);
                        p *= 0.125f;
                        float nm = fmaxf(mr, p);
                        float sc = __expf(mr - nm);
                        float e  = __expf(p - nm);
                        s = s*sc + e;
                        o = o*sc + e*__bfloat162float(vp[jj*64 + lane]);
                        mr = nm;
                    }
                    float ov = o / s;
                    float ovp = __shfl_xor(ov, 1);     // partner lane's value
                    if (!(lane & 1)){
                        uint32_t pk2 = (uint32_t)f2bf(ov) | ((uint32_t)f2bf(ovp) << 16);
                        sst32((uint32_t*)attnbf + (((size_t)b*512 + j*64 + lane) >> 1), pk2);
                    }
                }
            }
            gbar();

            // ============ P2: out-proj (+bias+resid) -> tmp + LN1 partials =
            {
                const unsigned long long* src = (const unsigned long long*)attnbf;
                #pragma unroll
                for (int i = 0; i < 4; ++i){
                    int e = tid + i*256; int m = e >> 6, cg = e & 63;
                    size_t gi = ((size_t)(b0+m)*64 + cg)*2;
                    union { unsigned long long q[2]; uint4 v; } u;
                    u.q[0] = sld64(src + gi); u.q[1] = sld64(src + gi + 1);
                    ALDS(cg, m) = u.v;
                }
                __syncthreads();
                const uint4* Bg = (const uint4*)(wsw + 1572864 + (size_t)l*262144);
                floatx4 acc = {};
                int nb = j*64 + w*16;
                for (int kb = 0; kb < 16; ++kb){
                    short8 af = as_short8(ALDS(kb*4 + qd, ln));
                    short8 bf = as_short8(Bg[(size_t)(kb*4 + qd)*512 + nb + ln]);
                    acc = __builtin_amdgcn_mfma_f32_16x16x32_bf16(af, bf, acc, 0, 0, 0);
                }
                int n = nb + ln;
                float psum[4], psq[4];
                #pragma unroll
                for (int r = 0; r < 4; ++r){
                    int row = qd*4 + r, b = b0 + row;
                    float v = acc[r] + out_b[l*512 + n] + h[(size_t)b*512 + n];
                    sst32(&tmp[(size_t)b*512 + n], f2u(v));
                    psum[r] = v; psq[r] = v*v;
                }
                #pragma unroll
                for (int off = 1; off < 16; off <<= 1){
                    #pragma unroll
                    for (int r = 0; r < 4; ++r){
                        psum[r] += __shfl_xor(psum[r], off);
                        psq[r]  += __shfl_xor(psq[r],  off);
                    }
                }
                if (ln == 0){
                    #pragma unroll
                    for (int r = 0; r < 4; ++r){ redS[w][qd][r] = psum[r]; redQ[w][qd][r] = psq[r]; }
                }
                __syncthreads();
                if (tid < 16){
                    int q2 = tid >> 2, r2 = tid & 3;
                    float sm = redS[0][q2][r2]+redS[1][q2][r2]+redS[2][q2][r2]+redS[3][q2][r2];
                    float sq = redQ[0][q2][r2]+redQ[1][q2][r2]+redQ[2][q2][r2]+redQ[3][q2][r2];
                    union { float f[2]; unsigned long long q; } u;
                    u.f[0] = sm; u.f[1] = sq;
                    sst64(&st1[((size_t)(b0+tid)*8 + j)*2], u.q);
                }
            }
            gbar();

            // ============ P3: LN1 finalize + FF1 (relu) -> ffbf ============
            {
                if (tid < 16){
                    float sm = 0.f, sq = 0.f;
                    #pragma unroll
                    for (int jj = 0; jj < 8; ++jj){
                        union { unsigned long long q; float f[2]; } u;
                        u.q = sld64(&st1[((size_t)(b0+tid)*8 + jj)*2]);
                        sm += u.f[0]; sq += u.f[1];
                    }
                    float mean = sm * (1.0f/512.0f);
                    float var  = sq * (1.0f/512.0f) - mean*mean;
                    meanLds[tid] = mean;
                    rstdLds[tid] = rsqrtf(var + 1e-5f);
                }
                __syncthreads();
                #pragma unroll
                for (int i = 0; i < 4; ++i){
                    int e = tid + i*256; int m = e >> 6, cg = e & 63;
                    int b = b0 + m;
                    float mean = meanLds[m], rs = rstdLds[m];
                    const float* tp = tmp + (size_t)b*512 + cg*8;
                    union { unsigned long long q[4]; float f[8]; } uu;
                    uu.q[0] = sld64(tp);     uu.q[1] = sld64(tp + 2);
                    uu.q[2] = sld64(tp + 4); uu.q[3] = sld64(tp + 6);
                    float hn[8];
                    union { ushort s[8]; uint4 v; } pk;
                    #pragma unroll
                    for (int k = 0; k < 8; ++k){
                        int d = cg*8 + k;
                        float nv = (uu.f[k] - mean)*rs*ln1_s[l*512 + d] + ln1_b[l*512 + d];
                        hn[k] = nv;
                        pk.s[k] = f2bf(nv);
                    }
                    ALDS(cg, m) = pk.v;
                    if ((cg >> 3) == j){     // materialize LN1-out (FF2 residual)
                        float4* hp = (float4*)(h + (size_t)b*512 + cg*8);
                        hp[0] = make_float4(hn[0],hn[1],hn[2],hn[3]);
                        hp[1] = make_float4(hn[4],hn[5],hn[6],hn[7]);
                    }
                }
                __syncthreads();
                const uint4* Bg = (const uint4*)(wsw + 2097152 + (size_t)l*1048576);
                floatx4 acc[4] = {};
                int nb = j*256 + w*64;
                for (int kb = 0; kb < 16; ++kb){
                    short8 af = as_short8(ALDS(kb*4 + qd, ln));
                    #pragma unroll
                    for (int c = 0; c < 4; ++c){
                        short8 bf = as_short8(Bg[(size_t)(kb*4 + qd)*2048 + nb + c*16 + ln]);
                        acc[c] = __builtin_amdgcn_mfma_f32_16x16x32_bf16(af, bf, acc[c], 0, 0, 0);
                    }
                }
                #pragma unroll
                for (int c = 0; c < 4; ++c){
                    #pragma unroll
                    for (int r = 0; r < 4; ++r){
                        int row = qd*4 + r, b = b0 + row;
                        int n = nb + c*16 + ln;
                        float v  = acc[c][r] + ff_b1[l*2048 + n];
                        float vr = fmaxf(v, 0.0f);
                        float vp = __shfl_xor(vr, 1);
                        if (!(ln & 1)){
                            uint32_t pk2 = (uint32_t)f2bf(vr) | ((uint32_t)f2bf(vp) << 16);
                            sst32((uint32_t*)ffbf + (((size_t)b*2048 + n) >> 1), pk2);
                        }
                    }
                }
            }
            gbar();

            // ============ P4: FF2 (+bias+resid) -> tmp + LN2 partials ======
            {
                const unsigned long long* src = (const unsigned long long*)ffbf;
                #pragma unroll
                for (int i = 0; i < 16; ++i){
                    int e = tid + i*256; int m = e >> 8, cg = e & 255;
                    size_t gi = ((size_t)(b0+m)*256 + cg)*2;
                    union { unsigned long long q[2]; uint4 v; } u;
                    u.q[0] = sld64(src + gi); u.q[1] = sld64(src + gi + 1);
                    ALDS(cg, m) = u.v;
                }
                __syncthreads();
                const uint4* Bg = (const uint4*)(wsw + 4194304 + (size_t)l*1048576);
                floatx4 acc = {};
                int nb = j*64 + w*16;
                for (int kb = 0; kb < 64; ++kb){
                    short8 af = as_short8(ALDS(kb*4 + qd, ln));
                    short8 bf = as_short8(Bg[(size_t)(kb*4 + qd)*512 + nb + ln]);
                    acc = __builtin_amdgcn_mfma_f32_16x16x32_bf16(af, bf, acc, 0, 0, 0);
                }
                int n = nb + ln;
                float psum[4], psq[4];
                #pragma unroll
                for (int r = 0; r < 4; ++r){
                    int row = qd*4 + r, b = b0 + row;
                    float v = acc[r] + ff_b2[l*512 + n] + h[(size_t)b*512 + n];
                    sst32(&tmp[(size_t)b*512 + n], f2u(v));
                    psum[r] = v; psq[r] = v*v;
                }
                #pragma unroll
                for (int off = 1; off < 16; off <<= 1){
                    #pragma unroll
                    for (int r = 0; r < 4; ++r){
                        psum[r] += __shfl_xor(psum[r], off);
                        psq[r]  += __shfl_xor(psq[r],  off);
                    }
                }
                if (ln == 0){
                    #pragma unroll
                    for (int r = 0; r < 4; ++r){ redS[w][qd][r] = psum[r]; redQ[w][qd][r] = psq[r]; }
                }
                __syncthreads();
                if (tid < 16){
                    int q2 = tid >> 2, r2 = tid & 3;
                    float sm = redS[0][q2][r2]+redS[1][q2][r2]+redS[2][q2][r2]+redS[3][q2][r2];
                    float sq = redQ[0][q2][r2]+redQ[1][q2][r2]+redQ[2][q2][r2]+redQ[3][q2][r2];
                    union { float f[2]; unsigned long long q; } u;
                    u.f[0] = sm; u.f[1] = sq;
                    sst64(&st2[((size_t)(b0+tid)*8 + j)*2], u.q);
                }
            }
            gbar();

            // ============ P5: LN2 -> (h,hbf) for l=0 | head partials l=1 ===
            {
                if (tid < 16){
                    float sm = 0.f, sq = 0.f;
                    #pragma unroll
                    for (int jj = 0; jj < 8; ++jj){
                        union { unsigned long long q; float f[2]; } u;
                        u.q = sld64(&st2[((size_t)(b0+tid)*8 + jj)*2]);
                        sm += u.f[0]; sq += u.f[1];
                    }
                    float mean = sm * (1.0f/512.0f);
                    float var  = sq * (1.0f/512.0f) - mean*mean;
                    meanLds[tid] = mean;
                    rstdLds[tid] = rsqrtf(var + 1e-5f);
                }
                __syncthreads();
                int r = tid >> 4, q16 = tid & 15;
                int b = b0 + r;
                int d0 = j*64 + q16*4;
                const float* tp = tmp + (size_t)b*512 + d0;
                union { unsigned long long q[2]; float f[4]; } uu;
                uu.q[0] = sld64(tp); uu.q[1] = sld64(tp + 2);
                float mean = meanLds[r], rs = rstdLds[r];
                float hn0 = (uu.f[0] - mean)*rs*ln2_s[l*512 + d0+0] + ln2_b[l*512 + d0+0];
                float hn1 = (uu.f[1] - mean)*rs*ln2_s[l*512 + d0+1] + ln2_b[l*512 + d0+1];
                float hn2 = (uu.f[2] - mean)*rs*ln2_s[l*512 + d0+2] + ln2_b[l*512 + d0+2];
                float hn3 = (uu.f[3] - mean)*rs*ln2_s[l*512 + d0+3] + ln2_b[l*512 + d0+3];
                if (l == 0){
                    *(float4*)(h + (size_t)b*512 + d0) = make_float4(hn0,hn1,hn2,hn3);
                    union { ushort s[4]; unsigned long long q; } pk;
                    pk.s[0]=f2bf(hn0); pk.s[1]=f2bf(hn1); pk.s[2]=f2bf(hn2); pk.s[3]=f2bf(hn3);
                    sst64((ushort*)hbf + (size_t)b*512 + d0, pk.q);
                } else {
                    float s0 = hn0*hw[(d0+0)*3+0] + hn1*hw[(d0+1)*3+0] + hn2*hw[(d0+2)*3+0] + hn3*hw[(d0+3)*3+0];
                    float s1 = hn0*hw[(d0+0)*3+1] + hn1*hw[(d0+1)*3+1] + hn2*hw[(d0+2)*3+1] + hn3*hw[(d0+3)*3+1];
                    float s2 = hn0*hw[(d0+0)*3+2] + hn1*hw[(d0+1)*3+2] + hn2*hw[(d0+2)*3+2] + hn3*hw[(d0+3)*3+2];
                    #pragma unroll
                    for (int off = 1; off < 16; off <<= 1){
                        s0 += __shfl_xor(s0, off);
                        s1 += __shfl_xor(s1, off);
                        s2 += __shfl_xor(s2, off);
                    }
                    if (q16 == 0){
                        float* yp = ypart + ((size_t)b*8 + j)*3;
                        sst32(yp + 0, f2u(s0));
                        sst32(yp + 1, f2u(s1));
                        sst32(yp + 2, f2u(s2));
                    }
                }
            }
            gbar();
        } // l
    } // t

    // final head output for t=15 (ypart released by the last gbar)
    if (j == 0 && tid < 48){
        int r = tid / 3, c = tid - r*3;
        float yv = hb[c];
        #pragma unroll
        for (int jj = 0; jj < 8; ++jj)
            yv += u2f(sld32(&ypart[((size_t)(b0+r)*8 + jj)*3 + c]));
        out[((size_t)(b0+r)*16 + 15)*3 + c] = yv;
    }
}

// ---------------------------------------------------------------------------
extern "C" void kernel_launch(void* const* d_in, const int* in_sizes, int n_in,
                              void* d_out, int out_size, void* d_ws, size_t ws_size,
                              hipStream_t stream)
{
    const float* x     = (const float*)d_in[0];
    const float* ip_w  = (const float*)d_in[1];
    const float* ip_b  = (const float*)d_in[2];
    const float* qkv_w = (const float*)d_in[3];
    const float* qkv_b = (const float*)d_in[4];
    const float* out_w = (const float*)d_in[5];
    const float* out_b = (const float*)d_in[6];
    const float* ln1_s = (const float*)d_in[7];
    const float* ln1_b = (const float*)d_in[8];
    const float* ff_w1 = (const float*)d_in[9];
    const float* ff_b1 = (const float*)d_in[10];
    const float* ff_w2 = (const float*)d_in[11];
    const float* ff_b2 = (const float*)d_in[12];
    const float* ln2_s = (const float*)d_in[13];
    const float* ln2_b = (const float*)d_in[14];
    const float* hw    = (const float*)d_in[15];
    const float* hb    = (const float*)d_in[16];
    float* outp = (float*)d_out;
    char* wsc   = (char*)d_ws;

    swz_k<<<dim3(32, 64, 8), 256, 0, stream>>>(qkv_w, out_w, ff_w1, ff_w2, (ushort*)d_ws);

    // Plain launch (NO cooperative launch: not graph-capturable). 256 blocks
    // with ~70KB LDS each are all-resident on 256 CUs -> no barrier deadlock.
    mega_k<<<dim3(256), dim3(256), 0, stream>>>(
        x, ip_w, ip_b, qkv_b, out_b, ln1_s, ln1_b,
        ff_b1, ff_b2, ln2_s, ln2_b, hw, hb, outp, wsc);
}

// Round 13
// 2834.437 us; speedup vs baseline: 2.2379x; 1.2461x over previous
//
#include <hip/hip_runtime.h>
#include <hip/hip_bf16.h>
#include <math.h>

// B=512, T=16, DIN=7, D=512, L=2, H=8, HD=64, FF=2048
// Persistent kernel: 32 groups x 16 batch rows, 8 blocks/group (column
// slices). All 16 timesteps x 2 layers in ONE launch; 8-block group
// barriers via relaxed system-scope (LLC) atomics; all cross-block data
// via LLC-bypass atomics (round 12 removed the redundant fences: -44%).
// Round 13: 512 threads/block (8 waves/CU, was 4) -- latency-bound with
// everything idle, so double TLP. QKV 12 tiles over 8 waves, attention
// 2 chains/wave, FF1 2 tiles/wave, out-proj on waves 0-3, FF2 K-split
// across wave pairs with LDS reduction (halves the K=2048 chain).

typedef __attribute__((__ext_vector_type__(8))) short short8;
typedef __attribute__((__ext_vector_type__(4))) float floatx4;

__device__ inline short8 as_short8(uint4 v){ union U{uint4 u; short8 s;} x; x.u=v; return x.s; }

__device__ inline ushort f2bf(float f){
    __hip_bfloat16 h = __float2bfloat16(f);
    ushort u; __builtin_memcpy(&u, &h, 2); return u;
}

// ---- system-scope (LLC-coherent) access helpers ------------------------
__device__ inline uint32_t sld32(const void* p){
    return __hip_atomic_load((const uint32_t*)p, __ATOMIC_RELAXED, __HIP_MEMORY_SCOPE_SYSTEM);
}
__device__ inline void sst32(void* p, uint32_t v){
    __hip_atomic_store((uint32_t*)p, v, __ATOMIC_RELAXED, __HIP_MEMORY_SCOPE_SYSTEM);
}
__device__ inline unsigned long long sld64(const void* p){
    return __hip_atomic_load((const unsigned long long*)p, __ATOMIC_RELAXED, __HIP_MEMORY_SCOPE_SYSTEM);
}
__device__ inline void sst64(void* p, unsigned long long v){
    __hip_atomic_store((unsigned long long*)p, v, __ATOMIC_RELAXED, __HIP_MEMORY_SCOPE_SYSTEM);
}
__device__ inline float u2f(uint32_t u){ float f; __builtin_memcpy(&f, &u, 4); return f; }
__device__ inline uint32_t f2u(float f){ uint32_t u; __builtin_memcpy(&u, &f, 4); return u; }

// ---- workspace byte offsets --------------------------------------------
#define WS_H      12582912   // float[512*512]      residual (block-private)
#define WS_TMP    13631488   // float[512*512]      pre-LN rows (cross-block)
#define WS_ST1    14680064   // float[512*8*2]      LN1 partial stats
#define WS_ST2    14712832   // float[512*8*2]      LN2 partial stats
#define WS_YPART  14745600   // float[512*8*3]      head partials
#define WS_BAR    14794752   // uint[512]           group barrier counters
#define WS_HBF    14796800   // bf16[512*512]       LN2(l=0) output, bf16
#define WS_ATTN   15321088   // bf16[512*512]       attention output
#define WS_FFBF   15845376   // bf16[512*2048]      relu(ff1) output
#define WS_KC     17942528   // bf16[2*512*8*16*64] K cache (block-private)
#define WS_VC     34719744   // bf16[2*512*8*16*64] V cache (block-private)

// ---------------------------------------------------------------------------
// Weight swizzle: fp32 W[K][N] -> bf16 16B groups of 8 k-consecutive values.
// Group linear index = (kb*4 + q)*N + n, holding W[kb*32+q*8 .. +7][n].
// blockIdx.z = matrix id: (mi = z>>1) 0:qkv 1:out 2:ff1 3:ff2, l = z&1.
// Zeroes ALL 512 group-barrier counters with SYSTEM-scope stores.
// ---------------------------------------------------------------------------
__global__ __launch_bounds__(256)
void swz_k(const float* __restrict__ qkv_w, const float* __restrict__ out_w,
           const float* __restrict__ ff1_w, const float* __restrict__ ff2_w,
           ushort* __restrict__ wsw)
{
    if (blockIdx.x == 0 && blockIdx.y == 0 && blockIdx.z == 0){
        unsigned* bar = (unsigned*)((char*)wsw + WS_BAR);
        for (int i = threadIdx.x; i < 512; i += 256)
            sst32(&bar[i], 0u);
    }
    int id = blockIdx.z; int l = id & 1; int mi = id >> 1;
    int K, N; const float* src; size_t doff;
    if (mi == 0)      { K = 512;  N = 1536; src = qkv_w + (size_t)l*786432;  doff = (size_t)l*786432; }
    else if (mi == 1) { K = 512;  N = 512;  src = out_w + (size_t)l*262144;  doff = 1572864 + (size_t)l*262144; }
    else if (mi == 2) { K = 512;  N = 2048; src = ff1_w + (size_t)l*1048576; doff = 2097152 + (size_t)l*1048576; }
    else              { K = 2048; N = 512;  src = ff2_w + (size_t)l*1048576; doff = 4194304 + (size_t)l*1048576; }
    int n0 = blockIdx.x * 64, k0 = blockIdx.y * 32;
    if (n0 >= N || k0 >= K) return;
    __shared__ float tt[32][64];
    int tid = threadIdx.x;
    int c = tid & 63, r = tid >> 6;
    #pragma unroll
    for (int i = 0; i < 8; ++i)
        tt[r + i*4][c] = src[(size_t)(k0 + r + i*4)*N + n0 + c];
    __syncthreads();
    int q = tid >> 6, n = tid & 63;
    union { ushort s[8]; uint4 v; } pk;
    #pragma unroll
    for (int i = 0; i < 8; ++i) pk.s[i] = f2bf(tt[q*8 + i][n]);
    ((uint4*)(wsw + doff))[(size_t)((k0 >> 5)*4 + q)*N + n0 + n] = pk.v;
}

// ---------------------------------------------------------------------------
// The persistent kernel. grid = 256 blocks x 512 threads (8 waves).
// group g = blockIdx & 31 (16 rows: b0 = g*16); member j = blockIdx >> 5.
// A-tiles (16 rows x K) in LDS, XOR swizzle slot(c,m) = c*16 + (m^(c&15)).
// ---------------------------------------------------------------------------
#define ALDS(c, m) aLds[(((c) << 4)) + (((m) ^ ((c) & 15)))]

__global__ __launch_bounds__(512, 1)
void mega_k(const float* __restrict__ x, const float* __restrict__ ip_w,
            const float* __restrict__ ip_b, const float* __restrict__ qkv_b,
            const float* __restrict__ out_b, const float* __restrict__ ln1_s,
            const float* __restrict__ ln1_b, const float* __restrict__ ff_b1,
            const float* __restrict__ ff_b2, const float* __restrict__ ln2_s,
            const float* __restrict__ ln2_b, const float* __restrict__ hw,
            const float* __restrict__ hb, float* __restrict__ out,
            char* __restrict__ ws)
{
    const ushort* wsw = (const ushort*)ws;
    float* h     = (float*)(ws + WS_H);
    float* tmp   = (float*)(ws + WS_TMP);
    float* st1   = (float*)(ws + WS_ST1);
    float* st2   = (float*)(ws + WS_ST2);
    float* ypart = (float*)(ws + WS_YPART);
    unsigned* bar = (unsigned*)(ws + WS_BAR);
    __hip_bfloat16* hbf    = (__hip_bfloat16*)(ws + WS_HBF);
    __hip_bfloat16* attnbf = (__hip_bfloat16*)(ws + WS_ATTN);
    __hip_bfloat16* ffbf   = (__hip_bfloat16*)(ws + WS_FFBF);
    __hip_bfloat16* kc0    = (__hip_bfloat16*)(ws + WS_KC);
    __hip_bfloat16* vc0    = (__hip_bfloat16*)(ws + WS_VC);

    const int g  = blockIdx.x & 31;   // group (16 batch rows)
    const int j  = blockIdx.x >> 5;   // column-slice member 0..7
    const int b0 = g * 16;
    const int tid  = threadIdx.x;
    const int lane = tid & 63, w = tid >> 6;      // w: 0..7
    const int qd = lane >> 4, ln = lane & 15;
    unsigned* cnt = bar + g*16;
    unsigned epoch = 0;

    __shared__ uint4 aLds[256*16];          // 64 KiB (K<=2048 A-tile)
    __shared__ float qLds[16][68];
    __shared__ float yLds[16][3];
    __shared__ float meanLds[16], rstdLds[16];
    __shared__ float redS[4][4][4], redQ[4][4][4];
    __shared__ floatx4 fred[4][64];         // FF2 K-split reduction (4KB)
    __shared__ float yred[4][16][3];

    auto gbar = [&]() {
        __syncthreads();      // each wave: vmcnt(0) drain -> bypass-stores at LLC
        epoch += 8;
        if (tid == 0){
            __hip_atomic_fetch_add(cnt, 1u, __ATOMIC_RELAXED, __HIP_MEMORY_SCOPE_SYSTEM);
            while (__hip_atomic_load(cnt, __ATOMIC_RELAXED, __HIP_MEMORY_SCOPE_SYSTEM) < epoch)
                __builtin_amdgcn_s_sleep(8);
        }
        __syncthreads();
    };

    for (int t = 0; t < 16; ++t){
        for (int l = 0; l < 2; ++l){
            __hip_bfloat16* kc = kc0 + (size_t)l*4194304;
            __hip_bfloat16* vc = vc0 + (size_t)l*4194304;

            // ============ P1: build A (layer input) + QKV + attention =====
            if (l == 1){
                const unsigned long long* src = (const unsigned long long*)hbf;
                #pragma unroll
                for (int i = 0; i < 2; ++i){
                    int e = tid + i*512; int m = e >> 6, cg = e & 63;
                    size_t gi = ((size_t)(b0+m)*64 + cg)*2;
                    union { unsigned long long q[2]; uint4 v; } u;
                    u.q[0] = sld64(src + gi); u.q[1] = sld64(src + gi + 1);
                    ALDS(cg, m) = u.v;
                }
            } else {
                if (t > 0){
                    if (tid < 48){
                        int r = tid / 3, c = tid - r*3;
                        float yv = hb[c];
                        #pragma unroll
                        for (int jj = 0; jj < 8; ++jj)
                            yv += u2f(sld32(&ypart[((size_t)(b0+r)*8 + jj)*3 + c]));
                        yLds[r][c] = yv;
                        if (j == 0)
                            out[((size_t)(b0+r)*16 + (t-1))*3 + c] = yv;
                    }
                    __syncthreads();
                }
                #pragma unroll
                for (int i = 0; i < 2; ++i){
                    int e = tid + i*512; int m = e >> 6, cg = e & 63;
                    int b = b0 + m;
                    const float* xr = x + ((size_t)b*16 + t)*7;
                    float f4, f5, f6;
                    if (t == 0){ f4 = xr[4]; f5 = xr[5]; f6 = xr[6]; }
                    else { f4 = yLds[m][0]; f5 = yLds[m][1]; f6 = yLds[m][2]; }
                    float x0 = xr[0], x1 = xr[1], x2 = xr[2], x3 = xr[3];
                    float hv[8];
                    union { ushort s[8]; uint4 v; } pk;
                    #pragma unroll
                    for (int k = 0; k < 8; ++k){
                        int d = cg*8 + k;
                        int e2 = d & ~1;
                        float div = expf(-(float)e2 * (9.210340371976184f / 512.0f));
                        float arg = (float)t * div;
                        float pe = (d & 1) ? cosf(arg) : sinf(arg);
                        float acc = ip_b[d] + pe
                            + x0*ip_w[0*512+d] + x1*ip_w[1*512+d]
                            + x2*ip_w[2*512+d] + x3*ip_w[3*512+d]
                            + f4*ip_w[4*512+d] + f5*ip_w[5*512+d] + f6*ip_w[6*512+d];
                        hv[k] = acc;
                        pk.s[k] = f2bf(acc);
                    }
                    ALDS(cg, m) = pk.v;
                    if ((cg >> 3) == j){
                        float4* hp = (float4*)(h + (size_t)(b0+m)*512 + cg*8);
                        hp[0] = make_float4(hv[0],hv[1],hv[2],hv[3]);
                        hp[1] = make_float4(hv[4],hv[5],hv[6],hv[7]);
                    }
                }
            }
            __syncthreads();

            { // QKV gemm: 12 tiles (s<3, c4<4) over 8 waves: w<4 ->2, w>=4 ->1
                const uint4* Bg = (const uint4*)(wsw + (size_t)l*786432);
                int s0 = (w < 4) ? (w >> 1) : 2;
                int cs = (w < 4) ? ((w & 1)*2) : (w - 4);
                int cN = (w < 4) ? 2 : 1;
                floatx4 acc[2] = {};
                for (int kb = 0; kb < 16; ++kb){
                    short8 af = as_short8(ALDS(kb*4 + qd, ln));
                    #pragma unroll
                    for (int c = 0; c < 2; ++c){
                        if (c < cN){
                            int n = s0*512 + j*64 + (cs + c)*16 + ln;
                            short8 bf = as_short8(Bg[(size_t)(kb*4 + qd)*1536 + n]);
                            acc[c] = __builtin_amdgcn_mfma_f32_16x16x32_bf16(af, bf, acc[c], 0, 0, 0);
                        }
                    }
                }
                #pragma unroll
                for (int c = 0; c < 2; ++c){
                    if (c < cN){
                        #pragma unroll
                        for (int r = 0; r < 4; ++r){
                            int row = qd*4 + r;
                            int cc = (cs + c)*16 + ln;          // 0..63 within s0
                            int n = s0*512 + j*64 + cc;
                            float v = acc[c][r] + qkv_b[l*1536 + n];
                            int b = b0 + row;
                            if (s0 == 0) qLds[row][cc] = v;
                            else if (s0 == 1) kc[(((size_t)b*8 + j)*16 + t)*64 + cc] = __float2bfloat16(v);
                            else              vc[(((size_t)b*8 + j)*16 + t)*64 + cc] = __float2bfloat16(v);
                        }
                    }
                }
            }
            __syncthreads();

            { // attention head j: 16 rows over 8 waves (2 each)
                #pragma unroll
                for (int i = 0; i < 2; ++i){
                    int m = w*2 + i;
                    int b = b0 + m;
                    float q = qLds[m][lane];
                    const __hip_bfloat16* kp = kc + ((size_t)b*8 + j)*1024;
                    const __hip_bfloat16* vp = vc + ((size_t)b*8 + j)*1024;
                    float mr = -1e30f, s = 0.0f, o = 0.0f;
                    for (int jj = 0; jj <= t; ++jj){
                        float p = q * __bfloat162float(kp[jj*64 + lane]);
                        #pragma unroll
                        for (int off = 32; off; off >>= 1) p += __shfl_xor(p, off);
                        p *= 0.125f;
                        float nm = fmaxf(mr, p);
                        float sc = __expf(mr - nm);
                        float e  = __expf(p - nm);
                        s = s*sc + e;
                        o = o*sc + e*__bfloat162float(vp[jj*64 + lane]);
                        mr = nm;
                    }
                    float ov = o / s;
                    float ovp = __shfl_xor(ov, 1);
                    if (!(lane & 1)){
                        uint32_t pk2 = (uint32_t)f2bf(ov) | ((uint32_t)f2bf(ovp) << 16);
                        sst32((uint32_t*)attnbf + (((size_t)b*512 + j*64 + lane) >> 1), pk2);
                    }
                }
            }
            gbar();

            // ============ P2: out-proj (+bias+resid) -> tmp + LN1 partials =
            {
                const unsigned long long* src = (const unsigned long long*)attnbf;
                #pragma unroll
                for (int i = 0; i < 2; ++i){
                    int e = tid + i*512; int m = e >> 6, cg = e & 63;
                    size_t gi = ((size_t)(b0+m)*64 + cg)*2;
                    union { unsigned long long q[2]; uint4 v; } u;
                    u.q[0] = sld64(src + gi); u.q[1] = sld64(src + gi + 1);
                    ALDS(cg, m) = u.v;
                }
                __syncthreads();
                if (w < 4){
                    const uint4* Bg = (const uint4*)(wsw + 1572864 + (size_t)l*262144);
                    floatx4 acc = {};
                    int nb = j*64 + w*16;
                    for (int kb = 0; kb < 16; ++kb){
                        short8 af = as_short8(ALDS(kb*4 + qd, ln));
                        short8 bf = as_short8(Bg[(size_t)(kb*4 + qd)*512 + nb + ln]);
                        acc = __builtin_amdgcn_mfma_f32_16x16x32_bf16(af, bf, acc, 0, 0, 0);
                    }
                    int n = nb + ln;
                    float psum[4], psq[4];
                    #pragma unroll
                    for (int r = 0; r < 4; ++r){
                        int row = qd*4 + r, b = b0 + row;
                        float v = acc[r] + out_b[l*512 + n] + h[(size_t)b*512 + n];
                        sst32(&tmp[(size_t)b*512 + n], f2u(v));
                        psum[r] = v; psq[r] = v*v;
                    }
                    #pragma unroll
                    for (int off = 1; off < 16; off <<= 1){
                        #pragma unroll
                        for (int r = 0; r < 4; ++r){
                            psum[r] += __shfl_xor(psum[r], off);
                            psq[r]  += __shfl_xor(psq[r],  off);
                        }
                    }
                    if (ln == 0){
                        #pragma unroll
                        for (int r = 0; r < 4; ++r){ redS[w][qd][r] = psum[r]; redQ[w][qd][r] = psq[r]; }
                    }
                }
                __syncthreads();
                if (tid < 16){
                    int q2 = tid >> 2, r2 = tid & 3;
                    float sm = redS[0][q2][r2]+redS[1][q2][r2]+redS[2][q2][r2]+redS[3][q2][r2];
                    float sq = redQ[0][q2][r2]+redQ[1][q2][r2]+redQ[2][q2][r2]+redQ[3][q2][r2];
                    union { float f[2]; unsigned long long q; } u;
                    u.f[0] = sm; u.f[1] = sq;
                    sst64(&st1[((size_t)(b0+tid)*8 + j)*2], u.q);
                }
            }
            gbar();

            // ============ P3: LN1 finalize + FF1 (relu) -> ffbf ============
            {
                if (tid < 16){
                    float sm = 0.f, sq = 0.f;
                    #pragma unroll
                    for (int jj = 0; jj < 8; ++jj){
                        union { unsigned long long q; float f[2]; } u;
                        u.q = sld64(&st1[((size_t)(b0+tid)*8 + jj)*2]);
                        sm += u.f[0]; sq += u.f[1];
                    }
                    float mean = sm * (1.0f/512.0f);
                    float var  = sq * (1.0f/512.0f) - mean*mean;
                    meanLds[tid] = mean;
                    rstdLds[tid] = rsqrtf(var + 1e-5f);
                }
                __syncthreads();
                #pragma unroll
                for (int i = 0; i < 2; ++i){
                    int e = tid + i*512; int m = e >> 6, cg = e & 63;
                    int b = b0 + m;
                    float mean = meanLds[m], rs = rstdLds[m];
                    const float* tp = tmp + (size_t)b*512 + cg*8;
                    union { unsigned long long q[4]; float f[8]; } uu;
                    uu.q[0] = sld64(tp);     uu.q[1] = sld64(tp + 2);
                    uu.q[2] = sld64(tp + 4); uu.q[3] = sld64(tp + 6);
                    float hn[8];
                    union { ushort s[8]; uint4 v; } pk;
                    #pragma unroll
                    for (int k = 0; k < 8; ++k){
                        int d = cg*8 + k;
                        float nv = (uu.f[k] - mean)*rs*ln1_s[l*512 + d] + ln1_b[l*512 + d];
                        hn[k] = nv;
                        pk.s[k] = f2bf(nv);
                    }
                    ALDS(cg, m) = pk.v;
                    if ((cg >> 3) == j){
                        float4* hp = (float4*)(h + (size_t)b*512 + cg*8);
                        hp[0] = make_float4(hn[0],hn[1],hn[2],hn[3]);
                        hp[1] = make_float4(hn[4],hn[5],hn[6],hn[7]);
                    }
                }
                __syncthreads();
                const uint4* Bg = (const uint4*)(wsw + 2097152 + (size_t)l*1048576);
                floatx4 acc[2] = {};
                int nb = j*256 + w*32;               // 2 tiles per wave
                for (int kb = 0; kb < 16; ++kb){
                    short8 af = as_short8(ALDS(kb*4 + qd, ln));
                    #pragma unroll
                    for (int c = 0; c < 2; ++c){
                        short8 bf = as_short8(Bg[(size_t)(kb*4 + qd)*2048 + nb + c*16 + ln]);
                        acc[c] = __builtin_amdgcn_mfma_f32_16x16x32_bf16(af, bf, acc[c], 0, 0, 0);
                    }
                }
                #pragma unroll
                for (int c = 0; c < 2; ++c){
                    #pragma unroll
                    for (int r = 0; r < 4; ++r){
                        int row = qd*4 + r, b = b0 + row;
                        int n = nb + c*16 + ln;
                        float v  = acc[c][r] + ff_b1[l*2048 + n];
                        float vr = fmaxf(v, 0.0f);
                        float vp = __shfl_xor(vr, 1);
                        if (!(ln & 1)){
                            uint32_t pk2 = (uint32_t)f2bf(vr) | ((uint32_t)f2bf(vp) << 16);
                            sst32((uint32_t*)ffbf + (((size_t)b*2048 + n) >> 1), pk2);
                        }
                    }
                }
            }
            gbar();

            // ============ P4: FF2 (+bias+resid) -> tmp + LN2 partials ======
            {
                const unsigned long long* src = (const unsigned long long*)ffbf;
                unsigned long long sb[16];
                #pragma unroll
                for (int i = 0; i < 8; ++i){
                    int e = tid + i*512;
                    size_t gi = ((size_t)(b0 + (e >> 8))*256 + (e & 255))*2;
                    sb[i*2]   = sld64(src + gi);
                    sb[i*2+1] = sld64(src + gi + 1);
                }
                #pragma unroll
                for (int i = 0; i < 8; ++i){
                    int e = tid + i*512; int m = e >> 8, cg = e & 255;
                    union { unsigned long long q[2]; uint4 v; } u;
                    u.q[0] = sb[i*2]; u.q[1] = sb[i*2+1];
                    ALDS(cg, m) = u.v;
                }
                __syncthreads();
                const uint4* Bg = (const uint4*)(wsw + 4194304 + (size_t)l*1048576);
                int tw = w & 3, hf = w >> 2;         // tile, K-half
                floatx4 acc = {};
                int nb = j*64 + tw*16;
                for (int kb = hf*32; kb < hf*32 + 32; ++kb){
                    short8 af = as_short8(ALDS(kb*4 + qd, ln));
                    short8 bf = as_short8(Bg[(size_t)(kb*4 + qd)*512 + nb + ln]);
                    acc = __builtin_amdgcn_mfma_f32_16x16x32_bf16(af, bf, acc, 0, 0, 0);
                }
                if (hf == 1) fred[tw][lane] = acc;
                __syncthreads();
                if (hf == 0){
                    floatx4 a2 = fred[tw][lane];
                    acc[0] += a2[0]; acc[1] += a2[1]; acc[2] += a2[2]; acc[3] += a2[3];
                    int n = nb + ln;
                    float psum[4], psq[4];
                    #pragma unroll
                    for (int r = 0; r < 4; ++r){
                        int row = qd*4 + r, b = b0 + row;
                        float v = acc[r] + ff_b2[l*512 + n] + h[(size_t)b*512 + n];
                        sst32(&tmp[(size_t)b*512 + n], f2u(v));
                        psum[r] = v; psq[r] = v*v;
                    }
                    #pragma unroll
                    for (int off = 1; off < 16; off <<= 1){
                        #pragma unroll
                        for (int r = 0; r < 4; ++r){
                            psum[r] += __shfl_xor(psum[r], off);
                            psq[r]  += __shfl_xor(psq[r],  off);
                        }
                    }
                    if (ln == 0){
                        #pragma unroll
                        for (int r = 0; r < 4; ++r){ redS[tw][qd][r] = psum[r]; redQ[tw][qd][r] = psq[r]; }
                    }
                }
                __syncthreads();
                if (tid < 16){
                    int q2 = tid >> 2, r2 = tid & 3;
                    float sm = redS[0][q2][r2]+redS[1][q2][r2]+redS[2][q2][r2]+redS[3][q2][r2];
                    float sq = redQ[0][q2][r2]+redQ[1][q2][r2]+redQ[2][q2][r2]+redQ[3][q2][r2];
                    union { float f[2]; unsigned long long q; } u;
                    u.f[0] = sm; u.f[1] = sq;
                    sst64(&st2[((size_t)(b0+tid)*8 + j)*2], u.q);
                }
            }
            gbar();

            // ============ P5: LN2 -> (h,hbf) for l=0 | head partials l=1 ===
            {
                if (tid < 16){
                    float sm = 0.f, sq = 0.f;
                    #pragma unroll
                    for (int jj = 0; jj < 8; ++jj){
                        union { unsigned long long q; float f[2]; } u;
                        u.q = sld64(&st2[((size_t)(b0+tid)*8 + jj)*2]);
                        sm += u.f[0]; sq += u.f[1];
                    }
                    float mean = sm * (1.0f/512.0f);
                    float var  = sq * (1.0f/512.0f) - mean*mean;
                    meanLds[tid] = mean;
                    rstdLds[tid] = rsqrtf(var + 1e-5f);
                }
                __syncthreads();
                if (tid < 256){
                    int r = tid >> 4, q16 = tid & 15;
                    int b = b0 + r;
                    int d0 = j*64 + q16*4;
                    const float* tp = tmp + (size_t)b*512 + d0;
                    union { unsigned long long q[2]; float f[4]; } uu;
                    uu.q[0] = sld64(tp); uu.q[1] = sld64(tp + 2);
                    float mean = meanLds[r], rs = rstdLds[r];
                    float hn0 = (uu.f[0] - mean)*rs*ln2_s[l*512 + d0+0] + ln2_b[l*512 + d0+0];
                    float hn1 = (uu.f[1] - mean)*rs*ln2_s[l*512 + d0+1] + ln2_b[l*512 + d0+1];
                    float hn2 = (uu.f[2] - mean)*rs*ln2_s[l*512 + d0+2] + ln2_b[l*512 + d0+2];
                    float hn3 = (uu.f[3] - mean)*rs*ln2_s[l*512 + d0+3] + ln2_b[l*512 + d0+3];
                    if (l == 0){
                        *(float4*)(h + (size_t)b*512 + d0) = make_float4(hn0,hn1,hn2,hn3);
                        union { ushort s[4]; unsigned long long q; } pk;
                        pk.s[0]=f2bf(hn0); pk.s[1]=f2bf(hn1); pk.s[2]=f2bf(hn2); pk.s[3]=f2bf(hn3);
                        sst64((ushort*)hbf + (size_t)b*512 + d0, pk.q);
                    } else {
                        float s0 = hn0*hw[(d0+0)*3+0] + hn1*hw[(d0+1)*3+0] + hn2*hw[(d0+2)*3+0] + hn3*hw[(d0+3)*3+0];
                        float s1 = hn0*hw[(d0+0)*3+1] + hn1*hw[(d0+1)*3+1] + hn2*hw[(d0+2)*3+1] + hn3*hw[(d0+3)*3+1];
                        float s2 = hn0*hw[(d0+0)*3+2] + hn1*hw[(d0+1)*3+2] + hn2*hw[(d0+2)*3+2] + hn3*hw[(d0+3)*3+2];
                        #pragma unroll
                        for (int off = 1; off < 16; off <<= 1){
                            s0 += __shfl_xor(s0, off);
                            s1 += __shfl_xor(s1, off);
                            s2 += __shfl_xor(s2, off);
                        }
                        if (q16 == 0){
                            yred[tid >> 6][r][0] = s0;
                            yred[tid >> 6][r][1] = s1;
                            yred[tid >> 6][r][2] = s2;
                        }
                    }
                }
                if (l == 1){
                    __syncthreads();
                    if (tid < 48){
                        int r = tid / 3, c = tid - r*3;
                        // rows r covered by wave (r>>2): yred[w'][r][c] holds
                        // the 16-lane-reduced partial for rows 4w'..4w'+3
                        float* yp = ypart + ((size_t)(b0+r)*8 + j)*3;
                        sst32(yp + c, f2u(yred[r >> 2][r][c]));
                    }
                }
            }
            gbar();
        } // l
    } // t

    // final head output for t=15
    if (j == 0 && tid < 48){
        int r = tid / 3, c = tid - r*3;
        float yv = hb[c];
        #pragma unroll
        for (int jj = 0; jj < 8; ++jj)
            yv += u2f(sld32(&ypart[((size_t)(b0+r)*8 + jj)*3 + c]));
        out[((size_t)(b0+r)*16 + 15)*3 + c] = yv;
    }
}

// ---------------------------------------------------------------------------
extern "C" void kernel_launch(void* const* d_in, const int* in_sizes, int n_in,
                              void* d_out, int out_size, void* d_ws, size_t ws_size,
                              hipStream_t stream)
{
    const float* x     = (const float*)d_in[0];
    const float* ip_w  = (const float*)d_in[1];
    const float* ip_b  = (const float*)d_in[2];
    const float* qkv_w = (const float*)d_in[3];
    const float* qkv_b = (const float*)d_in[4];
    const float* out_w = (const float*)d_in[5];
    const float* out_b = (const float*)d_in[6];
    const float* ln1_s = (const float*)d_in[7];
    const float* ln1_b = (const float*)d_in[8];
    const float* ff_w1 = (const float*)d_in[9];
    const float* ff_b1 = (const float*)d_in[10];
    const float* ff_w2 = (const float*)d_in[11];
    const float* ff_b2 = (const float*)d_in[12];
    const float* ln2_s = (const float*)d_in[13];
    const float* ln2_b = (const float*)d_in[14];
    const float* hw    = (const float*)d_in[15];
    const float* hb    = (const float*)d_in[16];
    float* outp = (float*)d_out;
    char* wsc   = (char*)d_ws;

    swz_k<<<dim3(32, 64, 8), 256, 0, stream>>>(qkv_w, out_w, ff_w1, ff_w2, (ushort*)d_ws);

    mega_k<<<dim3(256), dim3(512), 0, stream>>>(
        x, ip_w, ip_b, qkv_b, out_b, ln1_s, ln1_b,
        ff_b1, ff_b2, ln2_s, ln2_b, hw, hb, outp, wsc);
}

// Round 14
// 2560.606 us; speedup vs baseline: 2.4772x; 1.1069x over previous
//
#include <hip/hip_runtime.h>
#include <hip/hip_bf16.h>
#include <math.h>

// B=512, T=16, DIN=7, D=512, L=2, H=8, HD=64, FF=2048
// Persistent kernel: 32 groups x 16 batch rows, 8 blocks/group (column
// slices). All 16 timesteps x 2 layers in ONE launch; 8-block group
// barriers via relaxed system-scope (LLC) atomics; all cross-block data
// via LLC-bypass atomics. Round 12 removed redundant fences (-44%);
// round 13 went 4->8 waves/CU (-20%).
// Round 14: 1024 threads/block (16 waves/CU). QKV 1 tile/wave (12 busy),
// attention 1 row/wave, FF1 1 tile/wave, out-proj AND FF2 K-split 4-way
// across wave quartets with LDS reduction. Same phases, same barriers.

typedef __attribute__((__ext_vector_type__(8))) short short8;
typedef __attribute__((__ext_vector_type__(4))) float floatx4;

__device__ inline short8 as_short8(uint4 v){ union U{uint4 u; short8 s;} x; x.u=v; return x.s; }

__device__ inline ushort f2bf(float f){
    __hip_bfloat16 h = __float2bfloat16(f);
    ushort u; __builtin_memcpy(&u, &h, 2); return u;
}

// ---- system-scope (LLC-coherent) access helpers ------------------------
__device__ inline uint32_t sld32(const void* p){
    return __hip_atomic_load((const uint32_t*)p, __ATOMIC_RELAXED, __HIP_MEMORY_SCOPE_SYSTEM);
}
__device__ inline void sst32(void* p, uint32_t v){
    __hip_atomic_store((uint32_t*)p, v, __ATOMIC_RELAXED, __HIP_MEMORY_SCOPE_SYSTEM);
}
__device__ inline unsigned long long sld64(const void* p){
    return __hip_atomic_load((const unsigned long long*)p, __ATOMIC_RELAXED, __HIP_MEMORY_SCOPE_SYSTEM);
}
__device__ inline void sst64(void* p, unsigned long long v){
    __hip_atomic_store((unsigned long long*)p, v, __ATOMIC_RELAXED, __HIP_MEMORY_SCOPE_SYSTEM);
}
__device__ inline float u2f(uint32_t u){ float f; __builtin_memcpy(&f, &u, 4); return f; }
__device__ inline uint32_t f2u(float f){ uint32_t u; __builtin_memcpy(&u, &f, 4); return u; }

// ---- workspace byte offsets --------------------------------------------
#define WS_H      12582912   // float[512*512]      residual (block-private)
#define WS_TMP    13631488   // float[512*512]      pre-LN rows (cross-block)
#define WS_ST1    14680064   // float[512*8*2]      LN1 partial stats
#define WS_ST2    14712832   // float[512*8*2]      LN2 partial stats
#define WS_YPART  14745600   // float[512*8*3]      head partials
#define WS_BAR    14794752   // uint[512]           group barrier counters
#define WS_HBF    14796800   // bf16[512*512]       LN2(l=0) output, bf16
#define WS_ATTN   15321088   // bf16[512*512]       attention output
#define WS_FFBF   15845376   // bf16[512*2048]      relu(ff1) output
#define WS_KC     17942528   // bf16[2*512*8*16*64] K cache (block-private)
#define WS_VC     34719744   // bf16[2*512*8*16*64] V cache (block-private)

// ---------------------------------------------------------------------------
// Weight swizzle: fp32 W[K][N] -> bf16 16B groups of 8 k-consecutive values.
// Group linear index = (kb*4 + q)*N + n, holding W[kb*32+q*8 .. +7][n].
// blockIdx.z = matrix id: (mi = z>>1) 0:qkv 1:out 2:ff1 3:ff2, l = z&1.
// Zeroes ALL 512 group-barrier counters with SYSTEM-scope stores.
// ---------------------------------------------------------------------------
__global__ __launch_bounds__(256)
void swz_k(const float* __restrict__ qkv_w, const float* __restrict__ out_w,
           const float* __restrict__ ff1_w, const float* __restrict__ ff2_w,
           ushort* __restrict__ wsw)
{
    if (blockIdx.x == 0 && blockIdx.y == 0 && blockIdx.z == 0){
        unsigned* bar = (unsigned*)((char*)wsw + WS_BAR);
        for (int i = threadIdx.x; i < 512; i += 256)
            sst32(&bar[i], 0u);
    }
    int id = blockIdx.z; int l = id & 1; int mi = id >> 1;
    int K, N; const float* src; size_t doff;
    if (mi == 0)      { K = 512;  N = 1536; src = qkv_w + (size_t)l*786432;  doff = (size_t)l*786432; }
    else if (mi == 1) { K = 512;  N = 512;  src = out_w + (size_t)l*262144;  doff = 1572864 + (size_t)l*262144; }
    else if (mi == 2) { K = 512;  N = 2048; src = ff1_w + (size_t)l*1048576; doff = 2097152 + (size_t)l*1048576; }
    else              { K = 2048; N = 512;  src = ff2_w + (size_t)l*1048576; doff = 4194304 + (size_t)l*1048576; }
    int n0 = blockIdx.x * 64, k0 = blockIdx.y * 32;
    if (n0 >= N || k0 >= K) return;
    __shared__ float tt[32][64];
    int tid = threadIdx.x;
    int c = tid & 63, r = tid >> 6;
    #pragma unroll
    for (int i = 0; i < 8; ++i)
        tt[r + i*4][c] = src[(size_t)(k0 + r + i*4)*N + n0 + c];
    __syncthreads();
    int q = tid >> 6, n = tid & 63;
    union { ushort s[8]; uint4 v; } pk;
    #pragma unroll
    for (int i = 0; i < 8; ++i) pk.s[i] = f2bf(tt[q*8 + i][n]);
    ((uint4*)(wsw + doff))[(size_t)((k0 >> 5)*4 + q)*N + n0 + n] = pk.v;
}

// ---------------------------------------------------------------------------
// The persistent kernel. grid = 256 blocks x 1024 threads (16 waves).
// group g = blockIdx & 31 (16 rows: b0 = g*16); member j = blockIdx >> 5.
// A-tiles (16 rows x K) in LDS, XOR swizzle slot(c,m) = c*16 + (m^(c&15)).
// ---------------------------------------------------------------------------
#define ALDS(c, m) aLds[(((c) << 4)) + (((m) ^ ((c) & 15)))]

__global__ __launch_bounds__(1024, 1)
void mega_k(const float* __restrict__ x, const float* __restrict__ ip_w,
            const float* __restrict__ ip_b, const float* __restrict__ qkv_b,
            const float* __restrict__ out_b, const float* __restrict__ ln1_s,
            const float* __restrict__ ln1_b, const float* __restrict__ ff_b1,
            const float* __restrict__ ff_b2, const float* __restrict__ ln2_s,
            const float* __restrict__ ln2_b, const float* __restrict__ hw,
            const float* __restrict__ hb, float* __restrict__ out,
            char* __restrict__ ws)
{
    const ushort* wsw = (const ushort*)ws;
    float* h     = (float*)(ws + WS_H);
    float* tmp   = (float*)(ws + WS_TMP);
    float* st1   = (float*)(ws + WS_ST1);
    float* st2   = (float*)(ws + WS_ST2);
    float* ypart = (float*)(ws + WS_YPART);
    unsigned* bar = (unsigned*)(ws + WS_BAR);
    __hip_bfloat16* hbf    = (__hip_bfloat16*)(ws + WS_HBF);
    __hip_bfloat16* attnbf = (__hip_bfloat16*)(ws + WS_ATTN);
    __hip_bfloat16* ffbf   = (__hip_bfloat16*)(ws + WS_FFBF);
    __hip_bfloat16* kc0    = (__hip_bfloat16*)(ws + WS_KC);
    __hip_bfloat16* vc0    = (__hip_bfloat16*)(ws + WS_VC);

    const int g  = blockIdx.x & 31;   // group (16 batch rows)
    const int j  = blockIdx.x >> 5;   // column-slice member 0..7
    const int b0 = g * 16;
    const int tid  = threadIdx.x;
    const int lane = tid & 63, w = tid >> 6;      // w: 0..15
    const int qd = lane >> 4, ln = lane & 15;
    unsigned* cnt = bar + g*16;
    unsigned epoch = 0;

    __shared__ uint4 aLds[256*16];          // 64 KiB (K<=2048 A-tile)
    __shared__ float qLds[16][68];
    __shared__ float yLds[16][3];
    __shared__ float meanLds[16], rstdLds[16];
    __shared__ float redS[4][4][4], redQ[4][4][4];
    __shared__ floatx4 fred[4][3][64];      // K-split reduction (12KB)
    __shared__ float yred[4][16][3];

    auto gbar = [&]() {
        __syncthreads();      // each wave: vmcnt(0) drain -> bypass-stores at LLC
        epoch += 8;
        if (tid == 0){
            __hip_atomic_fetch_add(cnt, 1u, __ATOMIC_RELAXED, __HIP_MEMORY_SCOPE_SYSTEM);
            while (__hip_atomic_load(cnt, __ATOMIC_RELAXED, __HIP_MEMORY_SCOPE_SYSTEM) < epoch)
                __builtin_amdgcn_s_sleep(8);
        }
        __syncthreads();
    };

    for (int t = 0; t < 16; ++t){
        for (int l = 0; l < 2; ++l){
            __hip_bfloat16* kc = kc0 + (size_t)l*4194304;
            __hip_bfloat16* vc = vc0 + (size_t)l*4194304;

            // ============ P1: build A (layer input) + QKV + attention =====
            if (l == 1){
                const unsigned long long* src = (const unsigned long long*)hbf;
                int m = tid >> 6, cg = tid & 63;
                size_t gi = ((size_t)(b0+m)*64 + cg)*2;
                union { unsigned long long q[2]; uint4 v; } u;
                u.q[0] = sld64(src + gi); u.q[1] = sld64(src + gi + 1);
                ALDS(cg, m) = u.v;
            } else {
                if (t > 0){
                    if (tid < 48){
                        int r = tid / 3, c = tid - r*3;
                        float yv = hb[c];
                        #pragma unroll
                        for (int jj = 0; jj < 8; ++jj)
                            yv += u2f(sld32(&ypart[((size_t)(b0+r)*8 + jj)*3 + c]));
                        yLds[r][c] = yv;
                        if (j == 0)
                            out[((size_t)(b0+r)*16 + (t-1))*3 + c] = yv;
                    }
                    __syncthreads();
                }
                int m = tid >> 6, cg = tid & 63;
                int b = b0 + m;
                const float* xr = x + ((size_t)b*16 + t)*7;
                float f4, f5, f6;
                if (t == 0){ f4 = xr[4]; f5 = xr[5]; f6 = xr[6]; }
                else { f4 = yLds[m][0]; f5 = yLds[m][1]; f6 = yLds[m][2]; }
                float x0 = xr[0], x1 = xr[1], x2 = xr[2], x3 = xr[3];
                float hv[8];
                union { ushort s[8]; uint4 v; } pk;
                #pragma unroll
                for (int k = 0; k < 8; ++k){
                    int d = cg*8 + k;
                    int e2 = d & ~1;
                    float div = expf(-(float)e2 * (9.210340371976184f / 512.0f));
                    float arg = (float)t * div;
                    float pe = (d & 1) ? cosf(arg) : sinf(arg);
                    float acc = ip_b[d] + pe
                        + x0*ip_w[0*512+d] + x1*ip_w[1*512+d]
                        + x2*ip_w[2*512+d] + x3*ip_w[3*512+d]
                        + f4*ip_w[4*512+d] + f5*ip_w[5*512+d] + f6*ip_w[6*512+d];
                    hv[k] = acc;
                    pk.s[k] = f2bf(acc);
                }
                ALDS(cg, m) = pk.v;
                if ((cg >> 3) == j){
                    float4* hp = (float4*)(h + (size_t)b*512 + cg*8);
                    hp[0] = make_float4(hv[0],hv[1],hv[2],hv[3]);
                    hp[1] = make_float4(hv[4],hv[5],hv[6],hv[7]);
                }
            }
            __syncthreads();

            { // QKV gemm: 12 col-tiles, 1 per wave (waves 0..11)
                if (w < 12){
                    const uint4* Bg = (const uint4*)(wsw + (size_t)l*786432);
                    int s0 = w >> 2, cs = w & 3;
                    floatx4 acc = {};
                    for (int kb = 0; kb < 16; ++kb){
                        short8 af = as_short8(ALDS(kb*4 + qd, ln));
                        int n = s0*512 + j*64 + cs*16 + ln;
                        short8 bf = as_short8(Bg[(size_t)(kb*4 + qd)*1536 + n]);
                        acc = __builtin_amdgcn_mfma_f32_16x16x32_bf16(af, bf, acc, 0, 0, 0);
                    }
                    #pragma unroll
                    for (int r = 0; r < 4; ++r){
                        int row = qd*4 + r;
                        int cc = cs*16 + ln;            // 0..63 within s0
                        int n = s0*512 + j*64 + cc;
                        float v = acc[r] + qkv_b[l*1536 + n];
                        int b = b0 + row;
                        if (s0 == 0) qLds[row][cc] = v;
                        else if (s0 == 1) kc[(((size_t)b*8 + j)*16 + t)*64 + cc] = __float2bfloat16(v);
                        else              vc[(((size_t)b*8 + j)*16 + t)*64 + cc] = __float2bfloat16(v);
                    }
                }
            }
            __syncthreads();

            { // attention head j: 1 row-chain per wave
                int m = w;
                int b = b0 + m;
                float q = qLds[m][lane];
                const __hip_bfloat16* kp = kc + ((size_t)b*8 + j)*1024;
                const __hip_bfloat16* vp = vc + ((size_t)b*8 + j)*1024;
                float mr = -1e30f, s = 0.0f, o = 0.0f;
                for (int jj = 0; jj <= t; ++jj){
                    float p = q * __bfloat162float(kp[jj*64 + lane]);
                    #pragma unroll
                    for (int off = 32; off; off >>= 1) p += __shfl_xor(p, off);
                    p *= 0.125f;
                    float nm = fmaxf(mr, p);
                    float sc = __expf(mr - nm);
                    float e  = __expf(p - nm);
                    s = s*sc + e;
                    o = o*sc + e*__bfloat162float(vp[jj*64 + lane]);
                    mr = nm;
                }
                float ov = o / s;
                float ovp = __shfl_xor(ov, 1);
                if (!(lane & 1)){
                    uint32_t pk2 = (uint32_t)f2bf(ov) | ((uint32_t)f2bf(ovp) << 16);
                    sst32((uint32_t*)attnbf + (((size_t)b*512 + j*64 + lane) >> 1), pk2);
                }
            }
            gbar();

            // ============ P2: out-proj (+bias+resid) -> tmp + LN1 partials =
            {
                const unsigned long long* src = (const unsigned long long*)attnbf;
                {
                    int m = tid >> 6, cg = tid & 63;
                    size_t gi = ((size_t)(b0+m)*64 + cg)*2;
                    union { unsigned long long q[2]; uint4 v; } u;
                    u.q[0] = sld64(src + gi); u.q[1] = sld64(src + gi + 1);
                    ALDS(cg, m) = u.v;
                }
                __syncthreads();
                const uint4* Bg = (const uint4*)(wsw + 1572864 + (size_t)l*262144);
                int tw = w >> 2, hf = w & 3;           // tile, K-quarter
                floatx4 acc = {};
                int nb = j*64 + tw*16;
                for (int kb = hf*4; kb < hf*4 + 4; ++kb){
                    short8 af = as_short8(ALDS(kb*4 + qd, ln));
                    short8 bf = as_short8(Bg[(size_t)(kb*4 + qd)*512 + nb + ln]);
                    acc = __builtin_amdgcn_mfma_f32_16x16x32_bf16(af, bf, acc, 0, 0, 0);
                }
                if (hf) fred[tw][hf-1][lane] = acc;
                __syncthreads();
                if (hf == 0){
                    #pragma unroll
                    for (int q2 = 0; q2 < 3; ++q2){
                        floatx4 a2 = fred[tw][q2][lane];
                        acc[0] += a2[0]; acc[1] += a2[1]; acc[2] += a2[2]; acc[3] += a2[3];
                    }
                    int n = nb + ln;
                    float psum[4], psq[4];
                    #pragma unroll
                    for (int r = 0; r < 4; ++r){
                        int row = qd*4 + r, b = b0 + row;
                        float v = acc[r] + out_b[l*512 + n] + h[(size_t)b*512 + n];
                        sst32(&tmp[(size_t)b*512 + n], f2u(v));
                        psum[r] = v; psq[r] = v*v;
                    }
                    #pragma unroll
                    for (int off = 1; off < 16; off <<= 1){
                        #pragma unroll
                        for (int r = 0; r < 4; ++r){
                            psum[r] += __shfl_xor(psum[r], off);
                            psq[r]  += __shfl_xor(psq[r],  off);
                        }
                    }
                    if (ln == 0){
                        #pragma unroll
                        for (int r = 0; r < 4; ++r){ redS[tw][qd][r] = psum[r]; redQ[tw][qd][r] = psq[r]; }
                    }
                }
                __syncthreads();
                if (tid < 16){
                    int q2 = tid >> 2, r2 = tid & 3;
                    float sm = redS[0][q2][r2]+redS[1][q2][r2]+redS[2][q2][r2]+redS[3][q2][r2];
                    float sq = redQ[0][q2][r2]+redQ[1][q2][r2]+redQ[2][q2][r2]+redQ[3][q2][r2];
                    union { float f[2]; unsigned long long q; } u;
                    u.f[0] = sm; u.f[1] = sq;
                    sst64(&st1[((size_t)(b0+tid)*8 + j)*2], u.q);
                }
            }
            gbar();

            // ============ P3: LN1 finalize + FF1 (relu) -> ffbf ============
            {
                if (tid < 16){
                    float sm = 0.f, sq = 0.f;
                    #pragma unroll
                    for (int jj = 0; jj < 8; ++jj){
                        union { unsigned long long q; float f[2]; } u;
                        u.q = sld64(&st1[((size_t)(b0+tid)*8 + jj)*2]);
                        sm += u.f[0]; sq += u.f[1];
                    }
                    float mean = sm * (1.0f/512.0f);
                    float var  = sq * (1.0f/512.0f) - mean*mean;
                    meanLds[tid] = mean;
                    rstdLds[tid] = rsqrtf(var + 1e-5f);
                }
                __syncthreads();
                {
                    int m = tid >> 6, cg = tid & 63;
                    int b = b0 + m;
                    float mean = meanLds[m], rs = rstdLds[m];
                    const float* tp = tmp + (size_t)b*512 + cg*8;
                    union { unsigned long long q[4]; float f[8]; } uu;
                    uu.q[0] = sld64(tp);     uu.q[1] = sld64(tp + 2);
                    uu.q[2] = sld64(tp + 4); uu.q[3] = sld64(tp + 6);
                    float hn[8];
                    union { ushort s[8]; uint4 v; } pk;
                    #pragma unroll
                    for (int k = 0; k < 8; ++k){
                        int d = cg*8 + k;
                        float nv = (uu.f[k] - mean)*rs*ln1_s[l*512 + d] + ln1_b[l*512 + d];
                        hn[k] = nv;
                        pk.s[k] = f2bf(nv);
                    }
                    ALDS(cg, m) = pk.v;
                    if ((cg >> 3) == j){
                        float4* hp = (float4*)(h + (size_t)b*512 + cg*8);
                        hp[0] = make_float4(hn[0],hn[1],hn[2],hn[3]);
                        hp[1] = make_float4(hn[4],hn[5],hn[6],hn[7]);
                    }
                }
                __syncthreads();
                const uint4* Bg = (const uint4*)(wsw + 2097152 + (size_t)l*1048576);
                floatx4 acc = {};
                int nb = j*256 + w*16;                 // 1 tile per wave
                for (int kb = 0; kb < 16; ++kb){
                    short8 af = as_short8(ALDS(kb*4 + qd, ln));
                    short8 bf = as_short8(Bg[(size_t)(kb*4 + qd)*2048 + nb + ln]);
                    acc = __builtin_amdgcn_mfma_f32_16x16x32_bf16(af, bf, acc, 0, 0, 0);
                }
                #pragma unroll
                for (int r = 0; r < 4; ++r){
                    int row = qd*4 + r, b = b0 + row;
                    int n = nb + ln;
                    float v  = acc[r] + ff_b1[l*2048 + n];
                    float vr = fmaxf(v, 0.0f);
                    float vp = __shfl_xor(vr, 1);
                    if (!(ln & 1)){
                        uint32_t pk2 = (uint32_t)f2bf(vr) | ((uint32_t)f2bf(vp) << 16);
                        sst32((uint32_t*)ffbf + (((size_t)b*2048 + n) >> 1), pk2);
                    }
                }
            }
            gbar();

            // ============ P4: FF2 (+bias+resid) -> tmp + LN2 partials ======
            {
                const unsigned long long* src = (const unsigned long long*)ffbf;
                unsigned long long sb[8];
                #pragma unroll
                for (int i = 0; i < 4; ++i){
                    int e = tid + i*1024;
                    size_t gi = ((size_t)(b0 + (e >> 8))*256 + (e & 255))*2;
                    sb[i*2]   = sld64(src + gi);
                    sb[i*2+1] = sld64(src + gi + 1);
                }
                #pragma unroll
                for (int i = 0; i < 4; ++i){
                    int e = tid + i*1024; int m = e >> 8, cg = e & 255;
                    union { unsigned long long q[2]; uint4 v; } u;
                    u.q[0] = sb[i*2]; u.q[1] = sb[i*2+1];
                    ALDS(cg, m) = u.v;
                }
                __syncthreads();
                const uint4* Bg = (const uint4*)(wsw + 4194304 + (size_t)l*1048576);
                int tw = w >> 2, hf = w & 3;           // tile, K-quarter
                floatx4 acc = {};
                int nb = j*64 + tw*16;
                for (int kb = hf*16; kb < hf*16 + 16; ++kb){
                    short8 af = as_short8(ALDS(kb*4 + qd, ln));
                    short8 bf = as_short8(Bg[(size_t)(kb*4 + qd)*512 + nb + ln]);
                    acc = __builtin_amdgcn_mfma_f32_16x16x32_bf16(af, bf, acc, 0, 0, 0);
                }
                if (hf) fred[tw][hf-1][lane] = acc;
                __syncthreads();
                if (hf == 0){
                    #pragma unroll
                    for (int q2 = 0; q2 < 3; ++q2){
                        floatx4 a2 = fred[tw][q2][lane];
                        acc[0] += a2[0]; acc[1] += a2[1]; acc[2] += a2[2]; acc[3] += a2[3];
                    }
                    int n = nb + ln;
                    float psum[4], psq[4];
                    #pragma unroll
                    for (int r = 0; r < 4; ++r){
                        int row = qd*4 + r, b = b0 + row;
                        float v = acc[r] + ff_b2[l*512 + n] + h[(size_t)b*512 + n];
                        sst32(&tmp[(size_t)b*512 + n], f2u(v));
                        psum[r] = v; psq[r] = v*v;
                    }
                    #pragma unroll
                    for (int off = 1; off < 16; off <<= 1){
                        #pragma unroll
                        for (int r = 0; r < 4; ++r){
                            psum[r] += __shfl_xor(psum[r], off);
                            psq[r]  += __shfl_xor(psq[r],  off);
                        }
                    }
                    if (ln == 0){
                        #pragma unroll
                        for (int r = 0; r < 4; ++r){ redS[tw][qd][r] = psum[r]; redQ[tw][qd][r] = psq[r]; }
                    }
                }
                __syncthreads();
                if (tid < 16){
                    int q2 = tid >> 2, r2 = tid & 3;
                    float sm = redS[0][q2][r2]+redS[1][q2][r2]+redS[2][q2][r2]+redS[3][q2][r2];
                    float sq = redQ[0][q2][r2]+redQ[1][q2][r2]+redQ[2][q2][r2]+redQ[3][q2][r2];
                    union { float f[2]; unsigned long long q; } u;
                    u.f[0] = sm; u.f[1] = sq;
                    sst64(&st2[((size_t)(b0+tid)*8 + j)*2], u.q);
                }
            }
            gbar();

            // ============ P5: LN2 -> (h,hbf) for l=0 | head partials l=1 ===
            {
                if (tid < 16){
                    float sm = 0.f, sq = 0.f;
                    #pragma unroll
                    for (int jj = 0; jj < 8; ++jj){
                        union { unsigned long long q; float f[2]; } u;
                        u.q = sld64(&st2[((size_t)(b0+tid)*8 + jj)*2]);
                        sm += u.f[0]; sq += u.f[1];
                    }
                    float mean = sm * (1.0f/512.0f);
                    float var  = sq * (1.0f/512.0f) - mean*mean;
                    meanLds[tid] = mean;
                    rstdLds[tid] = rsqrtf(var + 1e-5f);
                }
                __syncthreads();
                if (tid < 256){
                    int r = tid >> 4, q16 = tid & 15;
                    int b = b0 + r;
                    int d0 = j*64 + q16*4;
                    const float* tp = tmp + (size_t)b*512 + d0;
                    union { unsigned long long q[2]; float f[4]; } uu;
                    uu.q[0] = sld64(tp); uu.q[1] = sld64(tp + 2);
                    float mean = meanLds[r], rs = rstdLds[r];
                    float hn0 = (uu.f[0] - mean)*rs*ln2_s[l*512 + d0+0] + ln2_b[l*512 + d0+0];
                    float hn1 = (uu.f[1] - mean)*rs*ln2_s[l*512 + d0+1] + ln2_b[l*512 + d0+1];
                    float hn2 = (uu.f[2] - mean)*rs*ln2_s[l*512 + d0+2] + ln2_b[l*512 + d0+2];
                    float hn3 = (uu.f[3] - mean)*rs*ln2_s[l*512 + d0+3] + ln2_b[l*512 + d0+3];
                    if (l == 0){
                        *(float4*)(h + (size_t)b*512 + d0) = make_float4(hn0,hn1,hn2,hn3);
                        union { ushort s[4]; unsigned long long q; } pk;
                        pk.s[0]=f2bf(hn0); pk.s[1]=f2bf(hn1); pk.s[2]=f2bf(hn2); pk.s[3]=f2bf(hn3);
                        sst64((ushort*)hbf + (size_t)b*512 + d0, pk.q);
                    } else {
                        float s0 = hn0*hw[(d0+0)*3+0] + hn1*hw[(d0+1)*3+0] + hn2*hw[(d0+2)*3+0] + hn3*hw[(d0+3)*3+0];
                        float s1 = hn0*hw[(d0+0)*3+1] + hn1*hw[(d0+1)*3+1] + hn2*hw[(d0+2)*3+1] + hn3*hw[(d0+3)*3+1];
                        float s2 = hn0*hw[(d0+0)*3+2] + hn1*hw[(d0+1)*3+2] + hn2*hw[(d0+2)*3+2] + hn3*hw[(d0+3)*3+2];
                        #pragma unroll
                        for (int off = 1; off < 16; off <<= 1){
                            s0 += __shfl_xor(s0, off);
                            s1 += __shfl_xor(s1, off);
                            s2 += __shfl_xor(s2, off);
                        }
                        if (q16 == 0){
                            yred[tid >> 6][r][0] = s0;
                            yred[tid >> 6][r][1] = s1;
                            yred[tid >> 6][r][2] = s2;
                        }
                    }
                }
                if (l == 1){
                    __syncthreads();
                    if (tid < 48){
                        int r = tid / 3, c = tid - r*3;
                        float* yp = ypart + ((size_t)(b0+r)*8 + j)*3;
                        sst32(yp + c, f2u(yred[r >> 2][r][c]));
                    }
                }
            }
            gbar();
        } // l
    } // t

    // final head output for t=15
    if (j == 0 && tid < 48){
        int r = tid / 3, c = tid - r*3;
        float yv = hb[c];
        #pragma unroll
        for (int jj = 0; jj < 8; ++jj)
            yv += u2f(sld32(&ypart[((size_t)(b0+r)*8 + jj)*3 + c]));
        out[((size_t)(b0+r)*16 + 15)*3 + c] = yv;
    }
}

// ---------------------------------------------------------------------------
extern "C" void kernel_launch(void* const* d_in, const int* in_sizes, int n_in,
                              void* d_out, int out_size, void* d_ws, size_t ws_size,
                              hipStream_t stream)
{
    const float* x     = (const float*)d_in[0];
    const float* ip_w  = (const float*)d_in[1];
    const float* ip_b  = (const float*)d_in[2];
    const float* qkv_w = (const float*)d_in[3];
    const float* qkv_b = (const float*)d_in[4];
    const float* out_w = (const float*)d_in[5];
    const float* out_b = (const float*)d_in[6];
    const float* ln1_s = (const float*)d_in[7];
    const float* ln1_b = (const float*)d_in[8];
    const float* ff_w1 = (const float*)d_in[9];
    const float* ff_b1 = (const float*)d_in[10];
    const float* ff_w2 = (const float*)d_in[11];
    const float* ff_b2 = (const float*)d_in[12];
    const float* ln2_s = (const float*)d_in[13];
    const float* ln2_b = (const float*)d_in[14];
    const float* hw    = (const float*)d_in[15];
    const float* hb    = (const float*)d_in[16];
    float* outp = (float*)d_out;
    char* wsc   = (char*)d_ws;

    swz_k<<<dim3(32, 64, 8), 256, 0, stream>>>(qkv_w, out_w, ff_w1, ff_w2, (ushort*)d_ws);

    mega_k<<<dim3(256), dim3(1024), 0, stream>>>(
        x, ip_w, ip_b, qkv_b, out_b, ln1_s, ln1_b,
        ff_b1, ff_b2, ln2_s, ln2_b, hw, hb, outp, wsc);
}

// Round 15
// 2454.754 us; speedup vs baseline: 2.5840x; 1.0431x over previous
//
#include <hip/hip_runtime.h>
#include <hip/hip_bf16.h>
#include <math.h>

// B=512, T=16, DIN=7, D=512, L=2, H=8, HD=64, FF=2048
// Persistent kernel: 32 groups x 16 batch rows, 8 blocks/group (column /
// K-slices). 16 timesteps x 2 layers in ONE launch.
// Round 15: TWO phases per (t,l) step (was 5), 64 group barriers (was 160).
//  PhaseA: [read tmpB -> LN2/head/embed locally] + QKV(head j) + attn(head j)
//          + out-proj K-slice partial -> unsafeAtomicAdd into tmpA[p]
//  PhaseB: read tmpA -> LN1 locally (full row) + FF1(256 cols) kept in LDS
//          + FF2 K-slice partial -> unsafeAtomicAdd into tmpB[p]
// All LN stats computed redundantly per block from the full 32KB tmp slab
// (no st1/st2/ypart/hbf/attnbf/ffbf exchanges). tmpA/tmpB double-buffered;
// buffer (s+1)&1 zeroed in PhaseB(s) (readers done < gbar1(s) < zero <
// gbar2(s) < writers). swz_k pre-zeroes all 4 tmp MB + barrier flags.

typedef __attribute__((__ext_vector_type__(8))) short short8;
typedef __attribute__((__ext_vector_type__(4))) float floatx4;

__device__ inline short8 as_short8(uint4 v){ union U{uint4 u; short8 s;} x; x.u=v; return x.s; }

__device__ inline ushort f2bf(float f){
    __hip_bfloat16 h = __float2bfloat16(f);
    ushort u; __builtin_memcpy(&u, &h, 2); return u;
}

// ---- system-scope (LLC) access helpers ---------------------------------
__device__ inline uint32_t sld32(const void* p){
    return __hip_atomic_load((const uint32_t*)p, __ATOMIC_RELAXED, __HIP_MEMORY_SCOPE_SYSTEM);
}
__device__ inline void sst32(void* p, uint32_t v){
    __hip_atomic_store((uint32_t*)p, v, __ATOMIC_RELAXED, __HIP_MEMORY_SCOPE_SYSTEM);
}
__device__ inline unsigned long long sld64(const void* p){
    return __hip_atomic_load((const unsigned long long*)p, __ATOMIC_RELAXED, __HIP_MEMORY_SCOPE_SYSTEM);
}
__device__ inline float u2f(uint32_t u){ float f; __builtin_memcpy(&f, &u, 4); return f; }

// ---- workspace byte offsets --------------------------------------------
#define WS_TMPA0 12582912   // float[512*512] out-proj accum, even steps
#define WS_TMPA1 13631488   // float[512*512] out-proj accum, odd steps
#define WS_TMPB0 14680064   // float[512*512] ff2 accum, even steps
#define WS_TMPB1 15728640   // float[512*512] ff2 accum, odd steps
#define WS_BAR   16777216   // uint[512] group barrier counters
#define WS_KC    16779264   // bf16[2*512*8*16*64] K cache (block-private)
#define WS_VC    33556480   // bf16[2*512*8*16*64] V cache (block-private)

// ---------------------------------------------------------------------------
// Weight swizzle: fp32 W[K][N] -> bf16 16B groups of 8 k-consecutive values.
// Group linear index = (kb*4 + q)*N + n, holding W[kb*32+q*8 .. +7][n].
// blockIdx.z = matrix id: (mi = z>>1) 0:qkv 1:out 2:ff1 3:ff2, l = z&1.
// z==0 plane zeroes the 4MB tmp region; block (0,0,0) zeroes barrier flags.
// ---------------------------------------------------------------------------
__global__ __launch_bounds__(256)
void swz_k(const float* __restrict__ qkv_w, const float* __restrict__ out_w,
           const float* __restrict__ ff1_w, const float* __restrict__ ff2_w,
           ushort* __restrict__ wsw)
{
    if (blockIdx.z == 0){
        float* tz = (float*)((char*)wsw + WS_TMPA0);
        int id = (blockIdx.y*gridDim.x + blockIdx.x)*256 + threadIdx.x;
        sst32(&tz[id], 0u);
        sst32(&tz[id + 524288], 0u);
        if (blockIdx.x == 0 && blockIdx.y == 0){
            unsigned* bar = (unsigned*)((char*)wsw + WS_BAR);
            for (int i = threadIdx.x; i < 512; i += 256)
                sst32(&bar[i], 0u);
        }
    }
    int id = blockIdx.z; int l = id & 1; int mi = id >> 1;
    int K, N; const float* src; size_t doff;
    if (mi == 0)      { K = 512;  N = 1536; src = qkv_w + (size_t)l*786432;  doff = (size_t)l*786432; }
    else if (mi == 1) { K = 512;  N = 512;  src = out_w + (size_t)l*262144;  doff = 1572864 + (size_t)l*262144; }
    else if (mi == 2) { K = 512;  N = 2048; src = ff1_w + (size_t)l*1048576; doff = 2097152 + (size_t)l*1048576; }
    else              { K = 2048; N = 512;  src = ff2_w + (size_t)l*1048576; doff = 4194304 + (size_t)l*1048576; }
    int n0 = blockIdx.x * 64, k0 = blockIdx.y * 32;
    if (n0 >= N || k0 >= K) return;
    __shared__ float tt[32][64];
    int tid = threadIdx.x;
    int c = tid & 63, r = tid >> 6;
    #pragma unroll
    for (int i = 0; i < 8; ++i)
        tt[r + i*4][c] = src[(size_t)(k0 + r + i*4)*N + n0 + c];
    __syncthreads();
    int q = tid >> 6, n = tid & 63;
    union { ushort s[8]; uint4 v; } pk;
    #pragma unroll
    for (int i = 0; i < 8; ++i) pk.s[i] = f2bf(tt[q*8 + i][n]);
    ((uint4*)(wsw + doff))[(size_t)((k0 >> 5)*4 + q)*N + n0 + n] = pk.v;
}

// ---------------------------------------------------------------------------
// The persistent kernel. grid = 256 blocks x 1024 threads (16 waves).
// group g = blockIdx & 31 (rows b0=g*16); member j = blockIdx >> 5 (K-slice).
// LDS tiles use XOR swizzle: slot(c,m) = (c<<4) + (m ^ (c&15)).
// ---------------------------------------------------------------------------
#define AOX(c, m) ((((c) << 4)) + (((m) ^ ((c) & 15))))

__global__ __launch_bounds__(1024, 1)
void mega_k(const float* __restrict__ x, const float* __restrict__ ip_w,
            const float* __restrict__ ip_b, const float* __restrict__ qkv_b,
            const float* __restrict__ out_b, const float* __restrict__ ln1_s,
            const float* __restrict__ ln1_b, const float* __restrict__ ff_b1,
            const float* __restrict__ ff_b2, const float* __restrict__ ln2_s,
            const float* __restrict__ ln2_b, const float* __restrict__ hw,
            const float* __restrict__ hb, float* __restrict__ out,
            char* __restrict__ ws)
{
    const ushort* wsw = (const ushort*)ws;
    unsigned* bar = (unsigned*)(ws + WS_BAR);
    __hip_bfloat16* kc0 = (__hip_bfloat16*)(ws + WS_KC);
    __hip_bfloat16* vc0 = (__hip_bfloat16*)(ws + WS_VC);

    const int g  = blockIdx.x & 31;
    const int j  = blockIdx.x >> 5;
    const int b0 = g * 16;
    const int tid  = threadIdx.x;
    const int lane = tid & 63, w = tid >> 6;      // w: 0..15
    const int qd = lane >> 4, ln = lane & 15;
    unsigned* cnt = bar + g*16;
    unsigned epoch = 0;

    __shared__ uint4 aLds[64*16];           // 16KB  A-tile (K=512, k-grouped)
    __shared__ uint4 aoLds[8*16];           // 2KB   attn-out tile (K=64)
    __shared__ uint4 ffLds[32*16];          // 8KB   relu(FF1) tile (K=256)
    __shared__ float hL[16][516];           // 33KB  layer-input / LN1-out, f32
    __shared__ float qLds[16][68];
    __shared__ float yLds[16][3];

    auto gbar = [&]() {
        __syncthreads();      // vmcnt(0) drain -> bypass stores + atomics at LLC
        epoch += 8;
        if (tid == 0){
            __hip_atomic_fetch_add(cnt, 1u, __ATOMIC_RELAXED, __HIP_MEMORY_SCOPE_SYSTEM);
            while (__hip_atomic_load(cnt, __ATOMIC_RELAXED, __HIP_MEMORY_SCOPE_SYSTEM) < epoch)
                __builtin_amdgcn_s_sleep(8);
        }
        __syncthreads();
    };

    for (int s = 0; s < 32; ++s){
        const int t = s >> 1, l = s & 1, p = s & 1;
        __hip_bfloat16* kc = kc0 + (size_t)l*4194304;
        __hip_bfloat16* vc = vc0 + (size_t)l*4194304;
        float* tmpA = (float*)(ws + WS_TMPA0 + (size_t)p*1048576);

        // ================= PHASE A =====================================
        // 1) produce layer input hL + A-tile (and y/out for s even >0)
        if (s == 0){
            int m = tid >> 6, cg = tid & 63;
            int b = b0 + m;
            const float* xr = x + ((size_t)b*16 + 0)*7;
            float hv[8]; union { ushort sx[8]; uint4 v; } pk;
            #pragma unroll
            for (int k = 0; k < 8; ++k){
                int d = cg*8 + k;
                float pe = (d & 1) ? 1.0f : 0.0f;      // t=0: sin0/cos0
                float acc = ip_b[d] + pe
                    + xr[0]*ip_w[d]        + xr[1]*ip_w[512 + d]
                    + xr[2]*ip_w[1024 + d] + xr[3]*ip_w[1536 + d]
                    + xr[4]*ip_w[2048 + d] + xr[5]*ip_w[2560 + d] + xr[6]*ip_w[3072 + d];
                hv[k] = acc; pk.sx[k] = f2bf(acc);
                hL[m][d] = acc;
            }
            aLds[AOX(cg, m)] = pk.v;
        } else {
            const float* tB = (const float*)(ws + WS_TMPB0 + (size_t)((s-1)&1)*1048576);
            const int lp = (s-1) & 1;                  // producing layer
            int m = w, b = b0 + m;
            const float* rowp = tB + (size_t)b*512 + lane*8;
            union { unsigned long long q[4]; float f[8]; } uu;
            uu.q[0] = sld64(rowp);     uu.q[1] = sld64(rowp + 2);
            uu.q[2] = sld64(rowp + 4); uu.q[3] = sld64(rowp + 6);
            float sm = 0.f, sq = 0.f;
            #pragma unroll
            for (int k = 0; k < 8; ++k){ sm += uu.f[k]; sq += uu.f[k]*uu.f[k]; }
            #pragma unroll
            for (int off = 32; off; off >>= 1){ sm += __shfl_xor(sm, off); sq += __shfl_xor(sq, off); }
            float mean = sm * (1.0f/512.0f);
            float var  = sq * (1.0f/512.0f) - mean*mean;
            float rs   = rsqrtf(var + 1e-5f);
            float hn[8];
            #pragma unroll
            for (int k = 0; k < 8; ++k){
                int d = lane*8 + k;
                hn[k] = (uu.f[k] - mean)*rs*ln2_s[lp*512 + d] + ln2_b[lp*512 + d];
            }
            if (l == 1){
                // hn IS layer-1 input: store hL + A-tile (c = d>>3 = lane)
                union { ushort sx[8]; uint4 v; } pk;
                #pragma unroll
                for (int k = 0; k < 8; ++k){ hL[m][lane*8 + k] = hn[k]; pk.sx[k] = f2bf(hn[k]); }
                aLds[AOX(lane, m)] = pk.v;
            } else {
                // head y from layer-1 LN2; then embed(t, y)
                float sr[3] = {};
                #pragma unroll
                for (int k = 0; k < 8; ++k){
                    int d = lane*8 + k;
                    sr[0] += hn[k]*hw[d*3+0]; sr[1] += hn[k]*hw[d*3+1]; sr[2] += hn[k]*hw[d*3+2];
                }
                #pragma unroll
                for (int off = 32; off; off >>= 1){
                    sr[0] += __shfl_xor(sr[0], off);
                    sr[1] += __shfl_xor(sr[1], off);
                    sr[2] += __shfl_xor(sr[2], off);
                }
                if (lane == 0){
                    #pragma unroll
                    for (int c = 0; c < 3; ++c){
                        float y = sr[c] + hb[c];
                        yLds[m][c] = y;
                        if (j == 0) out[((size_t)b*16 + (t-1))*3 + c] = y;
                    }
                }
                __syncthreads();
                int m2 = tid >> 6, cg = tid & 63;
                int b2 = b0 + m2;
                const float* xr = x + ((size_t)b2*16 + t)*7;
                float f4 = yLds[m2][0], f5 = yLds[m2][1], f6 = yLds[m2][2];
                float hv[8]; union { ushort sx[8]; uint4 v; } pk;
                #pragma unroll
                for (int k = 0; k < 8; ++k){
                    int d = cg*8 + k;
                    int e2 = d & ~1;
                    float div = expf(-(float)e2 * (9.210340371976184f / 512.0f));
                    float arg = (float)t * div;
                    float pe = (d & 1) ? cosf(arg) : sinf(arg);
                    float acc = ip_b[d] + pe
                        + xr[0]*ip_w[d]        + xr[1]*ip_w[512 + d]
                        + xr[2]*ip_w[1024 + d] + xr[3]*ip_w[1536 + d]
                        + f4*ip_w[2048 + d]    + f5*ip_w[2560 + d] + f6*ip_w[3072 + d];
                    hv[k] = acc; pk.sx[k] = f2bf(acc);
                    hL[m2][d] = acc;
                }
                aLds[AOX(cg, m2)] = pk.v;
            }
        }
        __syncthreads();

        { // 2) QKV gemm: head j's q/k/v (12 col-tiles over waves 0..11)
            if (w < 12){
                const uint4* Bg = (const uint4*)(wsw + (size_t)l*786432);
                int s0 = w >> 2, cs = w & 3;
                floatx4 acc = {};
                for (int kb = 0; kb < 16; ++kb){
                    short8 af = as_short8(aLds[AOX(kb*4 + qd, ln)]);
                    int n = s0*512 + j*64 + cs*16 + ln;
                    short8 bf = as_short8(Bg[(size_t)(kb*4 + qd)*1536 + n]);
                    acc = __builtin_amdgcn_mfma_f32_16x16x32_bf16(af, bf, acc, 0, 0, 0);
                }
                #pragma unroll
                for (int r = 0; r < 4; ++r){
                    int row = qd*4 + r;
                    int cc = cs*16 + ln;
                    int n = s0*512 + j*64 + cc;
                    float v = acc[r] + qkv_b[l*1536 + n];
                    int b = b0 + row;
                    if (s0 == 0) qLds[row][cc] = v;
                    else if (s0 == 1) kc[(((size_t)b*8 + j)*16 + t)*64 + cc] = __float2bfloat16(v);
                    else              vc[(((size_t)b*8 + j)*16 + t)*64 + cc] = __float2bfloat16(v);
                }
            }
        }
        __syncthreads();

        { // 3) attention head j: 1 row per wave -> aoLds (k-grouped bf16)
            int m = w, b = b0 + m;
            float q = qLds[m][lane];
            const __hip_bfloat16* kp = kc + ((size_t)b*8 + j)*1024;
            const __hip_bfloat16* vp = vc + ((size_t)b*8 + j)*1024;
            float mr = -1e30f, sden = 0.0f, o = 0.0f;
            for (int jj = 0; jj <= t; ++jj){
                float pdot = q * __bfloat162float(kp[jj*64 + lane]);
                #pragma unroll
                for (int off = 32; off; off >>= 1) pdot += __shfl_xor(pdot, off);
                pdot *= 0.125f;
                float nm = fmaxf(mr, pdot);
                float sc = __expf(mr - nm);
                float e  = __expf(pdot - nm);
                sden = sden*sc + e;
                o = o*sc + e*__bfloat162float(vp[jj*64 + lane]);
                mr = nm;
            }
            float ov = o / sden;
            ((ushort*)aoLds)[AOX(lane >> 3, m)*8 + (lane & 7)] = f2bf(ov);
        }
        __syncthreads();

        { // 4) out-proj K-slice (K=64): partial over W_out rows j*64..+63
            const uint4* Bg = (const uint4*)(wsw + 1572864 + (size_t)l*262144);
            #pragma unroll
            for (int c2 = 0; c2 < 2; ++c2){
                int n = (w*2 + c2)*16 + ln;
                floatx4 acc = {};
                #pragma unroll
                for (int kbl = 0; kbl < 2; ++kbl){
                    short8 af = as_short8(aoLds[AOX(kbl*4 + qd, ln)]);
                    short8 bf = as_short8(Bg[(size_t)((2*j + kbl)*4 + qd)*512 + n]);
                    acc = __builtin_amdgcn_mfma_f32_16x16x32_bf16(af, bf, acc, 0, 0, 0);
                }
                #pragma unroll
                for (int r = 0; r < 4; ++r){
                    int row = qd*4 + r, b = b0 + row;
                    float v = acc[r];
                    if (j == 0) v += out_b[l*512 + n] + hL[row][n];
                    unsafeAtomicAdd(&tmpA[(size_t)b*512 + n], v);
                }
            }
        }
        gbar();

        // ================= PHASE B =====================================
        {
            // zero next-step buffers (parity (s+1)&1): safe window proven
            float* zA = (float*)(ws + WS_TMPA0 + (size_t)((s+1)&1)*1048576);
            float* zB = (float*)(ws + WS_TMPB0 + (size_t)((s+1)&1)*1048576);
            int zr = b0 + (tid >> 6), zc = j*64 + (tid & 63);
            sst32(&zA[(size_t)zr*512 + zc], 0u);
            sst32(&zB[(size_t)zr*512 + zc], 0u);

            // 1) read tmpA full -> LN1 locally -> hL + A-tile
            int m = w, b = b0 + m;
            const float* rowp = tmpA + (size_t)b*512 + lane*8;
            union { unsigned long long q[4]; float f[8]; } uu;
            uu.q[0] = sld64(rowp);     uu.q[1] = sld64(rowp + 2);
            uu.q[2] = sld64(rowp + 4); uu.q[3] = sld64(rowp + 6);
            float sm = 0.f, sq = 0.f;
            #pragma unroll
            for (int k = 0; k < 8; ++k){ sm += uu.f[k]; sq += uu.f[k]*uu.f[k]; }
            #pragma unroll
            for (int off = 32; off; off >>= 1){ sm += __shfl_xor(sm, off); sq += __shfl_xor(sq, off); }
            float mean = sm * (1.0f/512.0f);
            float var  = sq * (1.0f/512.0f) - mean*mean;
            float rs   = rsqrtf(var + 1e-5f);
            union { ushort sx[8]; uint4 v; } pk;
            #pragma unroll
            for (int k = 0; k < 8; ++k){
                int d = lane*8 + k;
                float nv = (uu.f[k] - mean)*rs*ln1_s[l*512 + d] + ln1_b[l*512 + d];
                hL[m][d] = nv;
                pk.sx[k] = f2bf(nv);
            }
            aLds[AOX(lane, m)] = pk.v;
        }
        __syncthreads();

        { // 2) FF1: block j's 256 cols (1 col-tile per wave) -> ffLds
            const uint4* Bg = (const uint4*)(wsw + 2097152 + (size_t)l*1048576);
            floatx4 acc = {};
            int n = j*256 + w*16 + ln;
            for (int kb = 0; kb < 16; ++kb){
                short8 af = as_short8(aLds[AOX(kb*4 + qd, ln)]);
                short8 bf = as_short8(Bg[(size_t)(kb*4 + qd)*2048 + n]);
                acc = __builtin_amdgcn_mfma_f32_16x16x32_bf16(af, bf, acc, 0, 0, 0);
            }
            int kloc = w*16 + ln;
            #pragma unroll
            for (int r = 0; r < 4; ++r){
                int row = qd*4 + r;
                float vr = fmaxf(acc[r] + ff_b1[l*2048 + n], 0.0f);
                ((ushort*)ffLds)[AOX(kloc >> 3, row)*8 + (kloc & 7)] = f2bf(vr);
            }
        }
        __syncthreads();

        { // 3) FF2 K-slice (K=256): partial over W_ff2 rows j*256..+255
            const uint4* Bg = (const uint4*)(wsw + 4194304 + (size_t)l*1048576);
            float* tmpB = (float*)(ws + WS_TMPB0 + (size_t)p*1048576);
            #pragma unroll
            for (int c2 = 0; c2 < 2; ++c2){
                int n = (w*2 + c2)*16 + ln;
                floatx4 acc = {};
                #pragma unroll
                for (int kbl = 0; kbl < 8; ++kbl){
                    short8 af = as_short8(ffLds[AOX(kbl*4 + qd, ln)]);
                    short8 bf = as_short8(Bg[(size_t)((8*j + kbl)*4 + qd)*512 + n]);
                    acc = __builtin_amdgcn_mfma_f32_16x16x32_bf16(af, bf, acc, 0, 0, 0);
                }
                #pragma unroll
                for (int r = 0; r < 4; ++r){
                    int row = qd*4 + r, b = b0 + row;
                    float v = acc[r];
                    if (j == 0) v += ff_b2[l*512 + n] + hL[row][n];
                    unsafeAtomicAdd(&tmpB[(size_t)b*512 + n], v);
                }
            }
        }
        gbar();
    } // s

    // ---- final head output (t=15) from tmpB[1] ---------------------------
    if (j == 0){
        const float* tB = (const float*)(ws + WS_TMPB0 + (size_t)1*1048576);
        int m = w, b = b0 + m;
        const float* rowp = tB + (size_t)b*512 + lane*8;
        union { unsigned long long q[4]; float f[8]; } uu;
        uu.q[0] = sld64(rowp);     uu.q[1] = sld64(rowp + 2);
        uu.q[2] = sld64(rowp + 4); uu.q[3] = sld64(rowp + 6);
        float sm = 0.f, sq = 0.f;
        #pragma unroll
        for (int k = 0; k < 8; ++k){ sm += uu.f[k]; sq += uu.f[k]*uu.f[k]; }
        #pragma unroll
        for (int off = 32; off; off >>= 1){ sm += __shfl_xor(sm, off); sq += __shfl_xor(sq, off); }
        float mean = sm * (1.0f/512.0f);
        float var  = sq * (1.0f/512.0f) - mean*mean;
        float rs   = rsqrtf(var + 1e-5f);
        float sr[3] = {};
        #pragma unroll
        for (int k = 0; k < 8; ++k){
            int d = lane*8 + k;
            float hn = (uu.f[k] - mean)*rs*ln2_s[512 + d] + ln2_b[512 + d];
            sr[0] += hn*hw[d*3+0]; sr[1] += hn*hw[d*3+1]; sr[2] += hn*hw[d*3+2];
        }
        #pragma unroll
        for (int off = 32; off; off >>= 1){
            sr[0] += __shfl_xor(sr[0], off);
            sr[1] += __shfl_xor(sr[1], off);
            sr[2] += __shfl_xor(sr[2], off);
        }
        if (lane == 0){
            #pragma unroll
            for (int c = 0; c < 3; ++c)
                out[((size_t)b*16 + 15)*3 + c] = sr[c] + hb[c];
        }
    }
}

// ---------------------------------------------------------------------------
extern "C" void kernel_launch(void* const* d_in, const int* in_sizes, int n_in,
                              void* d_out, int out_size, void* d_ws, size_t ws_size,
                              hipStream_t stream)
{
    const float* x     = (const float*)d_in[0];
    const float* ip_w  = (const float*)d_in[1];
    const float* ip_b  = (const float*)d_in[2];
    const float* qkv_w = (const float*)d_in[3];
    const float* qkv_b = (const float*)d_in[4];
    const float* out_w = (const float*)d_in[5];
    const float* out_b = (const float*)d_in[6];
    const float* ln1_s = (const float*)d_in[7];
    const float* ln1_b = (const float*)d_in[8];
    const float* ff_w1 = (const float*)d_in[9];
    const float* ff_b1 = (const float*)d_in[10];
    const float* ff_w2 = (const float*)d_in[11];
    const float* ff_b2 = (const float*)d_in[12];
    const float* ln2_s = (const float*)d_in[13];
    const float* ln2_b = (const float*)d_in[14];
    const float* hw    = (const float*)d_in[15];
    const float* hb    = (const float*)d_in[16];
    float* outp = (float*)d_out;
    char* wsc   = (char*)d_ws;

    swz_k<<<dim3(32, 64, 8), 256, 0, stream>>>(qkv_w, out_w, ff_w1, ff_w2, (ushort*)d_ws);

    mega_k<<<dim3(256), dim3(1024), 0, stream>>>(
        x, ip_w, ip_b, qkv_b, out_b, ln1_s, ln1_b,
        ff_b1, ff_b2, ln2_s, ln2_b, hw, hb, outp, wsc);
}

// Round 16
// 2289.092 us; speedup vs baseline: 2.7710x; 1.0724x over previous
//
#include <hip/hip_runtime.h>
#include <hip/hip_bf16.h>
#include <math.h>

// B=512, T=16, DIN=7, D=512, L=2, H=8, HD=64, FF=2048
// Persistent kernel: 32 groups x 16 batch rows, 8 blocks/group (col/K
// slices), 2 phases + 2 barriers per (t,l). Round 12 dropped fences
// (-44%); r13/r14 TLP (-17%); r15 2-phase+atomics (-4%).
// Round 16: weight streaming via global_load_lds 4-deep per-wave pipeline
// (VGPR-free prefetch; 64KB/CU in flight vs ~4KB) for QKV/FF1/FF2.
// Counted vmcnt(3) waits, conflict-free lane*16B ds_read_b128 staging.

typedef __attribute__((__ext_vector_type__(8))) short short8;
typedef __attribute__((__ext_vector_type__(4))) float floatx4;

__device__ inline short8 as_short8(uint4 v){ union U{uint4 u; short8 s;} x; x.u=v; return x.s; }

__device__ inline ushort f2bf(float f){
    __hip_bfloat16 h = __float2bfloat16(f);
    ushort u; __builtin_memcpy(&u, &h, 2); return u;
}

// ---- system-scope (LLC) access helpers ---------------------------------
__device__ inline uint32_t sld32(const void* p){
    return __hip_atomic_load((const uint32_t*)p, __ATOMIC_RELAXED, __HIP_MEMORY_SCOPE_SYSTEM);
}
__device__ inline void sst32(void* p, uint32_t v){
    __hip_atomic_store((uint32_t*)p, v, __ATOMIC_RELAXED, __HIP_MEMORY_SCOPE_SYSTEM);
}
__device__ inline unsigned long long sld64(const void* p){
    return __hip_atomic_load((const unsigned long long*)p, __ATOMIC_RELAXED, __HIP_MEMORY_SCOPE_SYSTEM);
}
__device__ inline float u2f(uint32_t u){ float f; __builtin_memcpy(&f, &u, 4); return f; }

// async global->LDS DMA, 16B per lane (dest = wave-uniform base + lane*16)
__device__ inline void gld16(const void* g, void* l){
    __builtin_amdgcn_global_load_lds(
        (const __attribute__((address_space(1))) uint32_t*)(g),
        (__attribute__((address_space(3))) uint32_t*)(l), 16, 0, 0);
}

// ---- workspace byte offsets --------------------------------------------
#define WS_TMPA0 12582912   // float[512*512] out-proj accum, even steps
#define WS_TMPA1 13631488   // float[512*512] out-proj accum, odd steps
#define WS_TMPB0 14680064   // float[512*512] ff2 accum, even steps
#define WS_TMPB1 15728640   // float[512*512] ff2 accum, odd steps
#define WS_BAR   16777216   // uint[512] group barrier counters
#define WS_KC    16779264   // bf16[2*512*8*16*64] K cache (block-private)
#define WS_VC    33556480   // bf16[2*512*8*16*64] V cache (block-private)

// ---------------------------------------------------------------------------
// Weight swizzle: fp32 W[K][N] -> bf16 16B groups of 8 k-consecutive values.
// Group linear index = (kb*4 + q)*N + n, holding W[kb*32+q*8 .. +7][n].
// blockIdx.z = matrix id: (mi = z>>1) 0:qkv 1:out 2:ff1 3:ff2, l = z&1.
// z==0 plane zeroes the 4MB tmp region; block (0,0,0) zeroes barrier flags.
// ---------------------------------------------------------------------------
__global__ __launch_bounds__(256)
void swz_k(const float* __restrict__ qkv_w, const float* __restrict__ out_w,
           const float* __restrict__ ff1_w, const float* __restrict__ ff2_w,
           ushort* __restrict__ wsw)
{
    if (blockIdx.z == 0){
        float* tz = (float*)((char*)wsw + WS_TMPA0);
        int id = (blockIdx.y*gridDim.x + blockIdx.x)*256 + threadIdx.x;
        sst32(&tz[id], 0u);
        sst32(&tz[id + 524288], 0u);
        if (blockIdx.x == 0 && blockIdx.y == 0){
            unsigned* bar = (unsigned*)((char*)wsw + WS_BAR);
            for (int i = threadIdx.x; i < 512; i += 256)
                sst32(&bar[i], 0u);
        }
    }
    int id = blockIdx.z; int l = id & 1; int mi = id >> 1;
    int K, N; const float* src; size_t doff;
    if (mi == 0)      { K = 512;  N = 1536; src = qkv_w + (size_t)l*786432;  doff = (size_t)l*786432; }
    else if (mi == 1) { K = 512;  N = 512;  src = out_w + (size_t)l*262144;  doff = 1572864 + (size_t)l*262144; }
    else if (mi == 2) { K = 512;  N = 2048; src = ff1_w + (size_t)l*1048576; doff = 2097152 + (size_t)l*1048576; }
    else              { K = 2048; N = 512;  src = ff2_w + (size_t)l*1048576; doff = 4194304 + (size_t)l*1048576; }
    int n0 = blockIdx.x * 64, k0 = blockIdx.y * 32;
    if (n0 >= N || k0 >= K) return;
    __shared__ float tt[32][64];
    int tid = threadIdx.x;
    int c = tid & 63, r = tid >> 6;
    #pragma unroll
    for (int i = 0; i < 8; ++i)
        tt[r + i*4][c] = src[(size_t)(k0 + r + i*4)*N + n0 + c];
    __syncthreads();
    int q = tid >> 6, n = tid & 63;
    union { ushort s[8]; uint4 v; } pk;
    #pragma unroll
    for (int i = 0; i < 8; ++i) pk.s[i] = f2bf(tt[q*8 + i][n]);
    ((uint4*)(wsw + doff))[(size_t)((k0 >> 5)*4 + q)*N + n0 + n] = pk.v;
}

// ---------------------------------------------------------------------------
// The persistent kernel. grid = 256 blocks x 1024 threads (16 waves).
// group g = blockIdx & 31 (rows b0=g*16); member j = blockIdx >> 5 (K-slice).
// LDS tiles use XOR swizzle: slot(c,m) = (c<<4) + (m ^ (c&15)).
// ---------------------------------------------------------------------------
#define AOX(c, m) ((((c) << 4)) + (((m) ^ ((c) & 15))))

// 16-step, 4-slot per-wave DMA pipeline.
#define PSTEP(f, Ns, CONSUME) { \
    asm volatile("s_waitcnt vmcnt(" Ns ")" ::: "memory"); \
    __builtin_amdgcn_sched_barrier(0); \
    short8 _bf = as_short8(stg[w][(f)&3][lane]); \
    CONSUME(f, _bf); \
    asm volatile("s_waitcnt lgkmcnt(0)" ::: "memory"); }

#define PIPE16(ISSUE, CONSUME) \
    ISSUE(0); ISSUE(1); ISSUE(2); ISSUE(3); \
    PSTEP(0,"3",CONSUME)  ISSUE(4);  PSTEP(1,"3",CONSUME)  ISSUE(5); \
    PSTEP(2,"3",CONSUME)  ISSUE(6);  PSTEP(3,"3",CONSUME)  ISSUE(7); \
    PSTEP(4,"3",CONSUME)  ISSUE(8);  PSTEP(5,"3",CONSUME)  ISSUE(9); \
    PSTEP(6,"3",CONSUME)  ISSUE(10); PSTEP(7,"3",CONSUME)  ISSUE(11); \
    PSTEP(8,"3",CONSUME)  ISSUE(12); PSTEP(9,"3",CONSUME)  ISSUE(13); \
    PSTEP(10,"3",CONSUME) ISSUE(14); PSTEP(11,"3",CONSUME) ISSUE(15); \
    PSTEP(12,"3",CONSUME) PSTEP(13,"2",CONSUME) \
    PSTEP(14,"1",CONSUME) PSTEP(15,"0",CONSUME)

__global__ __launch_bounds__(1024, 1)
void mega_k(const float* __restrict__ x, const float* __restrict__ ip_w,
            const float* __restrict__ ip_b, const float* __restrict__ qkv_b,
            const float* __restrict__ out_b, const float* __restrict__ ln1_s,
            const float* __restrict__ ln1_b, const float* __restrict__ ff_b1,
            const float* __restrict__ ff_b2, const float* __restrict__ ln2_s,
            const float* __restrict__ ln2_b, const float* __restrict__ hw,
            const float* __restrict__ hb, float* __restrict__ out,
            char* __restrict__ ws)
{
    const ushort* wsw = (const ushort*)ws;
    unsigned* bar = (unsigned*)(ws + WS_BAR);
    __hip_bfloat16* kc0 = (__hip_bfloat16*)(ws + WS_KC);
    __hip_bfloat16* vc0 = (__hip_bfloat16*)(ws + WS_VC);

    const int g  = blockIdx.x & 31;
    const int j  = blockIdx.x >> 5;
    const int b0 = g * 16;
    const int tid  = threadIdx.x;
    const int lane = tid & 63, w = tid >> 6;      // w: 0..15
    const int qd = lane >> 4, ln = lane & 15;
    unsigned* cnt = bar + g*16;
    unsigned epoch = 0;

    __shared__ uint4 stg[16][4][64];        // 64KB per-wave DMA staging ring
    __shared__ uint4 aLds[64*16];           // 16KB  A-tile (K=512, k-grouped)
    __shared__ uint4 aoLds[8*16];           // 2KB   attn-out tile (K=64)
    __shared__ uint4 ffLds[32*16];          // 8KB   relu(FF1) tile (K=256)
    __shared__ float hL[16][516];           // 33KB  layer-input / LN1-out, f32
    __shared__ float qLds[16][68];
    __shared__ float yLds[16][3];

    auto gbar = [&]() {
        __syncthreads();      // vmcnt(0) drain -> bypass stores + atomics at LLC
        epoch += 8;
        if (tid == 0){
            __hip_atomic_fetch_add(cnt, 1u, __ATOMIC_RELAXED, __HIP_MEMORY_SCOPE_SYSTEM);
            while (__hip_atomic_load(cnt, __ATOMIC_RELAXED, __HIP_MEMORY_SCOPE_SYSTEM) < epoch)
                __builtin_amdgcn_s_sleep(2);
        }
        __syncthreads();
    };

    for (int s = 0; s < 32; ++s){
        const int t = s >> 1, l = s & 1, p = s & 1;
        __hip_bfloat16* kc = kc0 + (size_t)l*4194304;
        __hip_bfloat16* vc = vc0 + (size_t)l*4194304;
        float* tmpA = (float*)(ws + WS_TMPA0 + (size_t)p*1048576);

        // ================= PHASE A =====================================
        // 1) produce layer input hL + A-tile (and y/out for s even >0)
        if (s == 0){
            int m = tid >> 6, cg = tid & 63;
            int b = b0 + m;
            const float* xr = x + ((size_t)b*16 + 0)*7;
            float hv[8]; union { ushort sx[8]; uint4 v; } pk;
            #pragma unroll
            for (int k = 0; k < 8; ++k){
                int d = cg*8 + k;
                float pe = (d & 1) ? 1.0f : 0.0f;      // t=0: sin0/cos0
                float acc = ip_b[d] + pe
                    + xr[0]*ip_w[d]        + xr[1]*ip_w[512 + d]
                    + xr[2]*ip_w[1024 + d] + xr[3]*ip_w[1536 + d]
                    + xr[4]*ip_w[2048 + d] + xr[5]*ip_w[2560 + d] + xr[6]*ip_w[3072 + d];
                hv[k] = acc; pk.sx[k] = f2bf(acc);
                hL[m][d] = acc;
            }
            aLds[AOX(cg, m)] = pk.v;
        } else {
            const float* tB = (const float*)(ws + WS_TMPB0 + (size_t)((s-1)&1)*1048576);
            const int lp = (s-1) & 1;                  // producing layer
            int m = w, b = b0 + m;
            const float* rowp = tB + (size_t)b*512 + lane*8;
            union { unsigned long long q[4]; float f[8]; } uu;
            uu.q[0] = sld64(rowp);     uu.q[1] = sld64(rowp + 2);
            uu.q[2] = sld64(rowp + 4); uu.q[3] = sld64(rowp + 6);
            float sm = 0.f, sq = 0.f;
            #pragma unroll
            for (int k = 0; k < 8; ++k){ sm += uu.f[k]; sq += uu.f[k]*uu.f[k]; }
            #pragma unroll
            for (int off = 32; off; off >>= 1){ sm += __shfl_xor(sm, off); sq += __shfl_xor(sq, off); }
            float mean = sm * (1.0f/512.0f);
            float var  = sq * (1.0f/512.0f) - mean*mean;
            float rs   = rsqrtf(var + 1e-5f);
            float hn[8];
            #pragma unroll
            for (int k = 0; k < 8; ++k){
                int d = lane*8 + k;
                hn[k] = (uu.f[k] - mean)*rs*ln2_s[lp*512 + d] + ln2_b[lp*512 + d];
            }
            if (l == 1){
                union { ushort sx[8]; uint4 v; } pk;
                #pragma unroll
                for (int k = 0; k < 8; ++k){ hL[m][lane*8 + k] = hn[k]; pk.sx[k] = f2bf(hn[k]); }
                aLds[AOX(lane, m)] = pk.v;
            } else {
                float sr[3] = {};
                #pragma unroll
                for (int k = 0; k < 8; ++k){
                    int d = lane*8 + k;
                    sr[0] += hn[k]*hw[d*3+0]; sr[1] += hn[k]*hw[d*3+1]; sr[2] += hn[k]*hw[d*3+2];
                }
                #pragma unroll
                for (int off = 32; off; off >>= 1){
                    sr[0] += __shfl_xor(sr[0], off);
                    sr[1] += __shfl_xor(sr[1], off);
                    sr[2] += __shfl_xor(sr[2], off);
                }
                if (lane == 0){
                    #pragma unroll
                    for (int c = 0; c < 3; ++c){
                        float y = sr[c] + hb[c];
                        yLds[m][c] = y;
                        if (j == 0) out[((size_t)b*16 + (t-1))*3 + c] = y;
                    }
                }
                __syncthreads();
                int m2 = tid >> 6, cg = tid & 63;
                int b2 = b0 + m2;
                const float* xr = x + ((size_t)b2*16 + t)*7;
                float f4 = yLds[m2][0], f5 = yLds[m2][1], f6 = yLds[m2][2];
                float hv[8]; union { ushort sx[8]; uint4 v; } pk;
                #pragma unroll
                for (int k = 0; k < 8; ++k){
                    int d = cg*8 + k;
                    int e2 = d & ~1;
                    float div = expf(-(float)e2 * (9.210340371976184f / 512.0f));
                    float arg = (float)t * div;
                    float pe = (d & 1) ? cosf(arg) : sinf(arg);
                    float acc = ip_b[d] + pe
                        + xr[0]*ip_w[d]        + xr[1]*ip_w[512 + d]
                        + xr[2]*ip_w[1024 + d] + xr[3]*ip_w[1536 + d]
                        + f4*ip_w[2048 + d]    + f5*ip_w[2560 + d] + f6*ip_w[3072 + d];
                    hv[k] = acc; pk.sx[k] = f2bf(acc);
                    hL[m2][d] = acc;
                }
                aLds[AOX(cg, m2)] = pk.v;
            }
        }
        __syncthreads();

        { // 2) QKV gemm (head j): 12 col-tiles over waves 0..11, DMA pipeline
            if (w < 12){
                const uint4* Bg = (const uint4*)(wsw + (size_t)l*786432);
                int s0 = w >> 2, cs = w & 3;
                const int nidx = s0*512 + j*64 + cs*16 + ln;
                floatx4 acc = {};
#define QISS(f) gld16(&Bg[(size_t)((f)*4 + qd)*1536 + nidx], &stg[w][(f)&3][0])
#define QCON(f, bfr) acc = __builtin_amdgcn_mfma_f32_16x16x32_bf16( \
                    as_short8(aLds[AOX((f)*4 + qd, ln)]), bfr, acc, 0, 0, 0)
                PIPE16(QISS, QCON)
#undef QISS
#undef QCON
                #pragma unroll
                for (int r = 0; r < 4; ++r){
                    int row = qd*4 + r;
                    int cc = cs*16 + ln;
                    int n = s0*512 + j*64 + cc;
                    float v = acc[r] + qkv_b[l*1536 + n];
                    int b = b0 + row;
                    if (s0 == 0) qLds[row][cc] = v;
                    else if (s0 == 1) kc[(((size_t)b*8 + j)*16 + t)*64 + cc] = __float2bfloat16(v);
                    else              vc[(((size_t)b*8 + j)*16 + t)*64 + cc] = __float2bfloat16(v);
                }
            }
        }
        __syncthreads();

        { // 3) attention head j: 1 row per wave -> aoLds (k-grouped bf16)
            int m = w, b = b0 + m;
            float q = qLds[m][lane];
            const __hip_bfloat16* kp = kc + ((size_t)b*8 + j)*1024;
            const __hip_bfloat16* vp = vc + ((size_t)b*8 + j)*1024;
            float mr = -1e30f, sden = 0.0f, o = 0.0f;
            for (int jj = 0; jj <= t; ++jj){
                float pdot = q * __bfloat162float(kp[jj*64 + lane]);
                #pragma unroll
                for (int off = 32; off; off >>= 1) pdot += __shfl_xor(pdot, off);
                pdot *= 0.125f;
                float nm = fmaxf(mr, pdot);
                float sc = __expf(mr - nm);
                float e  = __expf(pdot - nm);
                sden = sden*sc + e;
                o = o*sc + e*__bfloat162float(vp[jj*64 + lane]);
                mr = nm;
            }
            float ov = o / sden;
            ((ushort*)aoLds)[AOX(lane >> 3, m)*8 + (lane & 7)] = f2bf(ov);
        }
        __syncthreads();

        { // 4) out-proj K-slice (K=64): partial over W_out rows j*64..+63
            const uint4* Bg = (const uint4*)(wsw + 1572864 + (size_t)l*262144);
            #pragma unroll
            for (int c2 = 0; c2 < 2; ++c2){
                int n = (w*2 + c2)*16 + ln;
                floatx4 acc = {};
                #pragma unroll
                for (int kbl = 0; kbl < 2; ++kbl){
                    short8 af = as_short8(aoLds[AOX(kbl*4 + qd, ln)]);
                    short8 bf = as_short8(Bg[(size_t)((2*j + kbl)*4 + qd)*512 + n]);
                    acc = __builtin_amdgcn_mfma_f32_16x16x32_bf16(af, bf, acc, 0, 0, 0);
                }
                #pragma unroll
                for (int r = 0; r < 4; ++r){
                    int row = qd*4 + r, b = b0 + row;
                    float v = acc[r];
                    if (j == 0) v += out_b[l*512 + n] + hL[row][n];
                    unsafeAtomicAdd(&tmpA[(size_t)b*512 + n], v);
                }
            }
        }
        gbar();

        // ================= PHASE B =====================================
        {
            // zero next-step buffers (parity (s+1)&1): safe window proven
            float* zA = (float*)(ws + WS_TMPA0 + (size_t)((s+1)&1)*1048576);
            float* zB = (float*)(ws + WS_TMPB0 + (size_t)((s+1)&1)*1048576);
            int zr = b0 + (tid >> 6), zc = j*64 + (tid & 63);
            sst32(&zA[(size_t)zr*512 + zc], 0u);
            sst32(&zB[(size_t)zr*512 + zc], 0u);

            // 1) read tmpA full -> LN1 locally -> hL + A-tile
            int m = w, b = b0 + m;
            const float* rowp = tmpA + (size_t)b*512 + lane*8;
            union { unsigned long long q[4]; float f[8]; } uu;
            uu.q[0] = sld64(rowp);     uu.q[1] = sld64(rowp + 2);
            uu.q[2] = sld64(rowp + 4); uu.q[3] = sld64(rowp + 6);
            float sm = 0.f, sq = 0.f;
            #pragma unroll
            for (int k = 0; k < 8; ++k){ sm += uu.f[k]; sq += uu.f[k]*uu.f[k]; }
            #pragma unroll
            for (int off = 32; off; off >>= 1){ sm += __shfl_xor(sm, off); sq += __shfl_xor(sq, off); }
            float mean = sm * (1.0f/512.0f);
            float var  = sq * (1.0f/512.0f) - mean*mean;
            float rs   = rsqrtf(var + 1e-5f);
            union { ushort sx[8]; uint4 v; } pk;
            #pragma unroll
            for (int k = 0; k < 8; ++k){
                int d = lane*8 + k;
                float nv = (uu.f[k] - mean)*rs*ln1_s[l*512 + d] + ln1_b[l*512 + d];
                hL[m][d] = nv;
                pk.sx[k] = f2bf(nv);
            }
            aLds[AOX(lane, m)] = pk.v;
        }
        __syncthreads();

        { // 2) FF1: block j's 256 cols (1 tile/wave), DMA pipeline -> ffLds
            const uint4* Bg = (const uint4*)(wsw + 2097152 + (size_t)l*1048576);
            const int n1 = j*256 + w*16 + ln;
            floatx4 acc = {};
#define F1ISS(f) gld16(&Bg[(size_t)((f)*4 + qd)*2048 + n1], &stg[w][(f)&3][0])
#define F1CON(f, bfr) acc = __builtin_amdgcn_mfma_f32_16x16x32_bf16( \
                as_short8(aLds[AOX((f)*4 + qd, ln)]), bfr, acc, 0, 0, 0)
            PIPE16(F1ISS, F1CON)
#undef F1ISS
#undef F1CON
            int kloc = w*16 + ln;
            #pragma unroll
            for (int r = 0; r < 4; ++r){
                int row = qd*4 + r;
                float vr = fmaxf(acc[r] + ff_b1[l*2048 + n1], 0.0f);
                ((ushort*)ffLds)[AOX(kloc >> 3, row)*8 + (kloc & 7)] = f2bf(vr);
            }
        }
        __syncthreads();

        { // 3) FF2 K-slice (K=256): DMA pipeline, partial -> tmpB atomics
            const uint4* Bg = (const uint4*)(wsw + 4194304 + (size_t)l*1048576);
            float* tmpB = (float*)(ws + WS_TMPB0 + (size_t)p*1048576);
            floatx4 acc2[2] = {};
            // frag f: c2 = f>>3 (output col pair), kbl = f&7 (K sub-block)
#define F2ISS(f) gld16(&Bg[(size_t)((8*j + ((f)&7))*4 + qd)*512 + (w*2 + ((f)>>3))*16 + ln], \
                       &stg[w][(f)&3][0])
#define F2CON(f, bfr) acc2[(f)>>3] = __builtin_amdgcn_mfma_f32_16x16x32_bf16( \
                as_short8(ffLds[AOX(((f)&7)*4 + qd, ln)]), bfr, acc2[(f)>>3], 0, 0, 0)
            PIPE16(F2ISS, F2CON)
#undef F2ISS
#undef F2CON
            #pragma unroll
            for (int c2 = 0; c2 < 2; ++c2){
                int n = (w*2 + c2)*16 + ln;
                #pragma unroll
                for (int r = 0; r < 4; ++r){
                    int row = qd*4 + r, b = b0 + row;
                    float v = acc2[c2][r];
                    if (j == 0) v += ff_b2[l*512 + n] + hL[row][n];
                    unsafeAtomicAdd(&tmpB[(size_t)b*512 + n], v);
                }
            }
        }
        gbar();
    } // s

    // ---- final head output (t=15) from tmpB[1] ---------------------------
    if (j == 0){
        const float* tB = (const float*)(ws + WS_TMPB0 + (size_t)1*1048576);
        int m = w, b = b0 + m;
        const float* rowp = tB + (size_t)b*512 + lane*8;
        union { unsigned long long q[4]; float f[8]; } uu;
        uu.q[0] = sld64(rowp);     uu.q[1] = sld64(rowp + 2);
        uu.q[2] = sld64(rowp + 4); uu.q[3] = sld64(rowp + 6);
        float sm = 0.f, sq = 0.f;
        #pragma unroll
        for (int k = 0; k < 8; ++k){ sm += uu.f[k]; sq += uu.f[k]*uu.f[k]; }
        #pragma unroll
        for (int off = 32; off; off >>= 1){ sm += __shfl_xor(sm, off); sq += __shfl_xor(sq, off); }
        float mean = sm * (1.0f/512.0f);
        float var  = sq * (1.0f/512.0f) - mean*mean;
        float rs   = rsqrtf(var + 1e-5f);
        float sr[3] = {};
        #pragma unroll
        for (int k = 0; k < 8; ++k){
            int d = lane*8 + k;
            float hn = (uu.f[k] - mean)*rs*ln2_s[512 + d] + ln2_b[512 + d];
            sr[0] += hn*hw[d*3+0]; sr[1] += hn*hw[d*3+1]; sr[2] += hn*hw[d*3+2];
        }
        #pragma unroll
        for (int off = 32; off; off >>= 1){
            sr[0] += __shfl_xor(sr[0], off);
            sr[1] += __shfl_xor(sr[1], off);
            sr[2] += __shfl_xor(sr[2], off);
        }
        if (lane == 0){
            #pragma unroll
            for (int c = 0; c < 3; ++c)
                out[((size_t)b*16 + 15)*3 + c] = sr[c] + hb[c];
        }
    }
}

// ---------------------------------------------------------------------------
extern "C" void kernel_launch(void* const* d_in, const int* in_sizes, int n_in,
                              void* d_out, int out_size, void* d_ws, size_t ws_size,
                              hipStream_t stream)
{
    const float* x     = (const float*)d_in[0];
    const float* ip_w  = (const float*)d_in[1];
    const float* ip_b  = (const float*)d_in[2];
    const float* qkv_w = (const float*)d_in[3];
    const float* qkv_b = (const float*)d_in[4];
    const float* out_w = (const float*)d_in[5];
    const float* out_b = (const float*)d_in[6];
    const float* ln1_s = (const float*)d_in[7];
    const float* ln1_b = (const float*)d_in[8];
    const float* ff_w1 = (const float*)d_in[9];
    const float* ff_b1 = (const float*)d_in[10];
    const float* ff_w2 = (const float*)d_in[11];
    const float* ff_b2 = (const float*)d_in[12];
    const float* ln2_s = (const float*)d_in[13];
    const float* ln2_b = (const float*)d_in[14];
    const float* hw    = (const float*)d_in[15];
    const float* hb    = (const float*)d_in[16];
    float* outp = (float*)d_out;
    char* wsc   = (char*)d_ws;

    swz_k<<<dim3(32, 64, 8), 256, 0, stream>>>(qkv_w, out_w, ff_w1, ff_w2, (ushort*)d_ws);

    mega_k<<<dim3(256), dim3(1024), 0, stream>>>(
        x, ip_w, ip_b, qkv_b, out_b, ln1_s, ln1_b,
        ff_b1, ff_b2, ln2_s, ln2_b, hw, hb, outp, wsc);
}